// Round 1
// baseline (887.988 us; speedup 1.0000x reference)
//
#include <hip/hip_runtime.h>

// CLAGCN forward on MI355X.
// R1: stats 2-level. R2: multi-block scan. R3: bf16 staging + dual agg +
// fused combine. R4: revert stats to atomicAdd. R5: wave/node agg, bf16 A/B,
// fewer dispatches. R6: fill payload 4B; middle GEMMs -> MFMA bf16.
// R7: kill CSR-build write amplification. Old fill_kernel scattered 1.6M
//     random 4B stores -> 112MB WRITE_SIZE (64B line write-back per store,
//     cross-XCD partial lines). Replaced count+fill with a 2-level bucket
//     sort: binA bins edges by dst>>10 through LDS chunk buffers (coalesced
//     256-512B flushes, 4B packed payload (dst&1023)<<16|src — needs N<=65536),
//     binHist builds per-node counts densely in LDS (removes count_kernel's
//     random atomics), binB places each bucket's edges into its contiguous
//     ~64KB cs window from a SINGLE workgroup (single XCD L2 -> lines fully
//     dirtied -> dense write-back).

#define DFEAT 128

typedef __attribute__((ext_vector_type(8))) short bf16x8;
typedef __attribute__((ext_vector_type(4))) float f32x4;

__device__ __forceinline__ unsigned short f2bf(float f) {
    unsigned u = __float_as_uint(f);
    u += 0x7fffu + ((u >> 16) & 1u);
    return (unsigned short)(u >> 16);
}
__device__ __forceinline__ float bf2f(unsigned short u) {
    return __uint_as_float((unsigned)u << 16);
}
__device__ __forceinline__ float4 bf4tof4(ushort4 u) {
    return make_float4(__uint_as_float((unsigned)u.x << 16),
                       __uint_as_float((unsigned)u.y << 16),
                       __uint_as_float((unsigned)u.z << 16),
                       __uint_as_float((unsigned)u.w << 16));
}

// ---------------- bucket sort: stage A (bin by dst>>10, LDS-buffered) ----------------
constexpr int EPB = 4096;   // edges per block
constexpr int BCAP = 64;    // LDS entries per bucket

__global__ __launch_bounds__(256) void binA_kernel(
    const int* __restrict__ src1, const int* __restrict__ dst1,
    const int* __restrict__ src2, const int* __restrict__ dst2,
    int* __restrict__ stg1, int* __restrict__ stg2,
    int* __restrict__ gcnt1, int* __restrict__ gcnt2, int E, int nbk, int scap) {
    const int *src, *dst;
    int *stg, *gcnt;
    if (blockIdx.y == 0) { src = src1; dst = dst1; stg = stg1; gcnt = gcnt1; }
    else                 { src = src2; dst = dst2; stg = stg2; gcnt = gcnt2; }
    __shared__ int bins[64][BCAP];
    __shared__ int bcnt[64];
    int tid = threadIdx.x;
    if (tid < 64) bcnt[tid] = 0;
    __syncthreads();
    int base = blockIdx.x * EPB;
    int wv = tid >> 6, ln = tid & 63;
    for (int r = 0; r < EPB; r += 256) {
        int i = base + r + tid;
        if (i < E) {
            int d = dst[i];
            int b = d >> 10;
            int v = ((d & 1023) << 16) | src[i];  // src < 65536 (N=50000)
            int p = atomicAdd(&bcnt[b], 1);
            if (p < BCAP) {
                bins[b][p] = v;
            } else {  // overflow (statistically ~never with uniform dst): direct
                int gp = atomicAdd(&gcnt[b], 1);
                stg[(size_t)b * scap + gp] = v;
            }
        }
        __syncthreads();
        // flush buckets with >=32 entries: coalesced 128-256B chunks
        for (int b = wv; b < nbk; b += 4) {
            int c = min(bcnt[b], BCAP);
            if (c >= 32) {
                int gp = 0;
                if (ln == 0) gp = atomicAdd(&gcnt[b], c);
                gp = __shfl(gp, 0);
                if (ln < c) stg[(size_t)b * scap + gp + ln] = bins[b][ln];
                if (ln == 0) bcnt[b] = 0;
            }
        }
        __syncthreads();
    }
    // residual flush (<32 entries per bucket)
    for (int b = wv; b < nbk; b += 4) {
        int c = min(bcnt[b], BCAP);
        if (c > 0) {
            int gp = 0;
            if (ln == 0) gp = atomicAdd(&gcnt[b], c);
            gp = __shfl(gp, 0);
            if (ln < c) stg[(size_t)b * scap + gp + ln] = bins[b][ln];
        }
    }
}

// ---------------- bucket sort: per-bucket node histogram (replaces count) ----------------
__global__ __launch_bounds__(256) void binhist_kernel(
    const int* __restrict__ stg1, const int* __restrict__ stg2,
    const int* __restrict__ gcnt1, const int* __restrict__ gcnt2,
    int* __restrict__ cnt1, int* __restrict__ cnt2, int n, int scap) {
    const int *stg, *gcnt;
    int* cnt;
    if (blockIdx.y == 0) { stg = stg1; gcnt = gcnt1; cnt = cnt1; }
    else                 { stg = stg2; gcnt = gcnt2; cnt = cnt2; }
    int b = blockIdx.x;
    __shared__ int hist[1024];
    int t = threadIdx.x;
    for (int i = t; i < 1024; i += 256) hist[i] = 0;
    __syncthreads();
    int c = gcnt[b];
    const int* s = stg + (size_t)b * scap;
    for (int i = t; i < c; i += 256) atomicAdd(&hist[s[i] >> 16], 1);
    __syncthreads();
    int base = b << 10;
    for (int i = t; i < 1024; i += 256) {
        int node = base + i;
        if (node < n) cnt[node] = hist[i];
    }
}

// ---------------- bucket sort: stage B (final CSR placement, 1 WG/bucket) ----------------
__global__ __launch_bounds__(256) void binB_kernel(
    const int* __restrict__ stg1, const int* __restrict__ stg2,
    const int* __restrict__ gcnt1, const int* __restrict__ gcnt2,
    const int* __restrict__ rp1, const int* __restrict__ rp2,
    int* __restrict__ fl1, int* __restrict__ fl2,
    int* __restrict__ cs1, int* __restrict__ cs2, int scap) {
    const int *stg, *gcnt, *rp;
    int *fl, *cs;
    if (blockIdx.y == 0) { stg = stg1; gcnt = gcnt1; rp = rp1; fl = fl1; cs = cs1; }
    else                 { stg = stg2; gcnt = gcnt2; rp = rp2; fl = fl2; cs = cs2; }
    int b = blockIdx.x;
    int c = gcnt[b];
    const int* s = stg + (size_t)b * scap;
    int base = b << 10;
    for (int i = threadIdx.x; i < c; i += 256) {
        int v = s[i];
        int d = base + (v >> 16);
        int pos = rp[d] + atomicAdd(&fl[d], 1);
        cs[pos] = v & 0xFFFF;
    }
}

// ---------------- CSR scan (unchanged) ----------------
__global__ __launch_bounds__(256) void blocksum_kernel(const int* __restrict__ c1,
                                                       const int* __restrict__ c2,
                                                       int* __restrict__ bs, int n, int nb) {
    const int* c = blockIdx.y ? c2 : c1;
    int* out = bs + (size_t)blockIdx.y * nb;
    int t = threadIdx.x;
    int base = blockIdx.x * 2048 + t * 8;
    int s = 0;
#pragma unroll
    for (int i = 0; i < 8; ++i) {
        int idx = base + i;
        if (idx < n) s += c[idx];
    }
    __shared__ int red[256];
    red[t] = s;
    __syncthreads();
    for (int o = 128; o > 0; o >>= 1) {
        if (t < o) red[t] += red[t + o];
        __syncthreads();
    }
    if (t == 0) out[blockIdx.x] = red[0];
}

__global__ void scansums_kernel(int* __restrict__ bs, int nb, int* __restrict__ rp1,
                                int* __restrict__ rp2, int n, int E, float* __restrict__ stats) {
    int t = threadIdx.x;  // 64 threads
    if (t < 2) {
        int* b = bs + (size_t)t * nb;
        int run = 0;
        for (int i = 0; i < nb; ++i) {
            int v = b[i];
            b[i] = run;
            run += v;
        }
        (t ? rp2 : rp1)[n] = E;
    }
    for (int i = t; i < 512; i += 64) stats[i] = 0.f;
}

__global__ __launch_bounds__(256) void writerp_kernel(const int* __restrict__ c1,
                                                      const int* __restrict__ c2,
                                                      const int* __restrict__ bs,
                                                      int* __restrict__ rp1, int* __restrict__ rp2,
                                                      float* __restrict__ dv1,
                                                      float* __restrict__ dv2, int n, int nb) {
    const int* c = blockIdx.y ? c2 : c1;
    int* rp = blockIdx.y ? rp2 : rp1;
    float* dv = blockIdx.y ? dv2 : dv1;
    int boff = bs[(size_t)blockIdx.y * nb + blockIdx.x];
    int t = threadIdx.x;
    int base = blockIdx.x * 2048 + t * 8;
    int v[8];
    int s = 0;
#pragma unroll
    for (int i = 0; i < 8; ++i) {
        int idx = base + i;
        v[i] = (idx < n) ? c[idx] : 0;
        s += v[i];
    }
    __shared__ int red[256];
    red[t] = s;
    __syncthreads();
    for (int o = 1; o < 256; o <<= 1) {
        int x = (t >= o) ? red[t - o] : 0;
        __syncthreads();
        red[t] += x;
        __syncthreads();
    }
    int run = boff + red[t] - s;
#pragma unroll
    for (int i = 0; i < 8; ++i) {
        int idx = base + i;
        if (idx < n) {
            rp[idx] = run;
            dv[idx] = rsqrtf((float)(v[i] + 1));  // +1 self-loop
            run += v[i];
        }
    }
}

// ---------------- dual aggregation: one wave per node ----------------
template <int FV, typename OutT>
__global__ __launch_bounds__(256) void dualagg_kernel(
    const unsigned short* __restrict__ h1, const unsigned short* __restrict__ h2,
    const int* __restrict__ rp1, const int* __restrict__ cs1, const float* __restrict__ dv1,
    const int* __restrict__ rp2, const int* __restrict__ cs2, const float* __restrict__ dv2,
    const float* __restrict__ bias, OutT* __restrict__ o1, OutT* __restrict__ o2, int n) {
    constexpr int COLS = FV * 4;
    const unsigned short* h;
    const int *rp, *cs;
    const float* dv;
    OutT* out;
    if (blockIdx.y == 0) { h = h1; rp = rp1; cs = cs1; dv = dv1; out = o1; }
    else                 { h = h2; rp = rp2; cs = cs2; dv = dv2; out = o2; }
    int wid = blockIdx.x * 4 + (threadIdx.x >> 6);
    if (wid >= n) return;
    int lane = threadIdx.x & 63;
    int half = lane >> 5;
    int l = lane & 31;
    bool act = (l < FV);
    float dn = dv[wid];
    float4 acc = make_float4(0.f, 0.f, 0.f, 0.f);
    int e0 = rp[wid], e1 = rp[wid + 1];
    int e = e0 + half;
    for (; e + 6 < e1; e += 8) {
        int sa = cs[e], sb = cs[e + 2], sc = cs[e + 4], sd = cs[e + 6];
        float wa = dv[sa] * dn, wb = dv[sb] * dn, wc = dv[sc] * dn, wd = dv[sd] * dn;
        if (act) {
            float4 ha = bf4tof4(((const ushort4*)(h + (size_t)sa * COLS))[l]);
            float4 hb = bf4tof4(((const ushort4*)(h + (size_t)sb * COLS))[l]);
            float4 hc = bf4tof4(((const ushort4*)(h + (size_t)sc * COLS))[l]);
            float4 hd = bf4tof4(((const ushort4*)(h + (size_t)sd * COLS))[l]);
            acc.x = fmaf(wa, ha.x, acc.x); acc.y = fmaf(wa, ha.y, acc.y);
            acc.z = fmaf(wa, ha.z, acc.z); acc.w = fmaf(wa, ha.w, acc.w);
            acc.x = fmaf(wb, hb.x, acc.x); acc.y = fmaf(wb, hb.y, acc.y);
            acc.z = fmaf(wb, hb.z, acc.z); acc.w = fmaf(wb, hb.w, acc.w);
            acc.x = fmaf(wc, hc.x, acc.x); acc.y = fmaf(wc, hc.y, acc.y);
            acc.z = fmaf(wc, hc.z, acc.z); acc.w = fmaf(wc, hc.w, acc.w);
            acc.x = fmaf(wd, hd.x, acc.x); acc.y = fmaf(wd, hd.y, acc.y);
            acc.z = fmaf(wd, hd.z, acc.z); acc.w = fmaf(wd, hd.w, acc.w);
        }
    }
    for (; e < e1; e += 2) {
        int sa = cs[e];
        float wa = dv[sa] * dn;
        if (act) {
            float4 ha = bf4tof4(((const ushort4*)(h + (size_t)sa * COLS))[l]);
            acc.x = fmaf(wa, ha.x, acc.x); acc.y = fmaf(wa, ha.y, acc.y);
            acc.z = fmaf(wa, ha.z, acc.z); acc.w = fmaf(wa, ha.w, acc.w);
        }
    }
    acc.x += __shfl_xor(acc.x, 32);
    acc.y += __shfl_xor(acc.y, 32);
    acc.z += __shfl_xor(acc.z, 32);
    acc.w += __shfl_xor(acc.w, 32);
    if (half == 0 && act) {
        float w = dn * dn;  // self-loop norm
        float4 hv = bf4tof4(((const ushort4*)(h + (size_t)wid * COLS))[l]);
        acc.x = fmaf(w, hv.x, acc.x); acc.y = fmaf(w, hv.y, acc.y);
        acc.z = fmaf(w, hv.z, acc.z); acc.w = fmaf(w, hv.w, acc.w);
        float4 b = ((const float4*)bias)[l];
        acc.x += b.x; acc.y += b.y; acc.z += b.z; acc.w += b.w;
        if constexpr (sizeof(OutT) == 4) {
            ((float4*)((float*)out + (size_t)wid * COLS))[l] = acc;
        } else {
            ushort4 o;
            o.x = f2bf(acc.x); o.y = f2bf(acc.y); o.z = f2bf(acc.z); o.w = f2bf(acc.w);
            ((ushort4*)((unsigned short*)out + (size_t)wid * COLS))[l] = o;
        }
    }
}

// ---------------- Layer-1 quad GEMM ----------------
__global__ __launch_bounds__(256) void gemm_l1_kernel(
    const float* __restrict__ x1a, const float* __restrict__ x1b, const float* __restrict__ x2a,
    const float* __restrict__ x2b, const float* __restrict__ Wi, unsigned short* __restrict__ H1,
    unsigned short* __restrict__ H2, int nrows) {
    constexpr int CG = 16;
    const float* X = (blockIdx.y == 0) ? x1a : (blockIdx.y == 1) ? x1b
                     : (blockIdx.y == 2) ? x2a : x2b;
    const float* W = Wi + (blockIdx.y & 1) * 128 * 64;
    unsigned short* Y = (blockIdx.y < 2) ? H1 : H2;
    int ocol = (int)(blockIdx.y & 1) * 64;
    __shared__ float Ws[32][64];
    __shared__ float Xs[64][32];
    int tid = threadIdx.x;
    int row0 = blockIdx.x * 64;
    int cg = tid % CG;
    int rg = tid / CG;
    float4 acc[4];
#pragma unroll
    for (int i = 0; i < 4; ++i) acc[i] = make_float4(0.f, 0.f, 0.f, 0.f);
    for (int kc = 0; kc < 4; ++kc) {
        for (int i = tid; i < 32 * CG; i += 256) {
            int r = i / CG, c = i % CG;
            *(float4*)&Ws[r][c * 4] = *(const float4*)(W + (size_t)(kc * 32 + r) * 64 + c * 4);
        }
        for (int i = tid; i < 64 * 8; i += 256) {
            int r = i / 8, c = i % 8;
            int gr = row0 + r;
            float4 v = make_float4(0.f, 0.f, 0.f, 0.f);
            if (gr < nrows) v = *(const float4*)(X + (size_t)gr * DFEAT + kc * 32 + c * 4);
            *(float4*)&Xs[r][c * 4] = v;
        }
        __syncthreads();
#pragma unroll
        for (int k = 0; k < 32; ++k) {
            float4 w = *(float4*)&Ws[k][cg * 4];
#pragma unroll
            for (int i = 0; i < 4; ++i) {
                float a = Xs[rg * 4 + i][k];
                acc[i].x = fmaf(a, w.x, acc[i].x);
                acc[i].y = fmaf(a, w.y, acc[i].y);
                acc[i].z = fmaf(a, w.z, acc[i].z);
                acc[i].w = fmaf(a, w.w, acc[i].w);
            }
        }
        __syncthreads();
    }
#pragma unroll
    for (int i = 0; i < 4; ++i) {
        int r = row0 + rg * 4 + i;
        if (r < nrows) {
            ushort4 o;
            o.x = f2bf(acc[i].x); o.y = f2bf(acc[i].y);
            o.z = f2bf(acc[i].z); o.w = f2bf(acc[i].w);
            *(ushort4*)(Y + (size_t)r * DFEAT + ocol + cg * 4) = o;
        }
    }
}

// ---------------- prepW: Wm (2x128x128 fp32) -> bf16 transposed [l][kc][col][kk] ----------------
__global__ __launch_bounds__(256) void prepW_kernel(const float* __restrict__ Wm,
                                                    unsigned short* __restrict__ Wt) {
    int o = blockIdx.x * 256 + threadIdx.x;  // 16384 per layer
    int l = blockIdx.y;
    int kk = o & 31;
    int col = (o >> 5) & 127;
    int kc = o >> 12;
    int k = kc * 32 + kk;
    Wt[(size_t)l * 16384 + o] = f2bf(Wm[(size_t)l * 16384 + (size_t)k * 128 + col]);
}

// ---------------- MFMA fused GEMM (128->128): x = w1*relu(bn(A)) + w2*relu(bn(B)) ----------------
__global__ __launch_bounds__(256) void gemm_mfma_kernel(
    const unsigned short* __restrict__ Abf, const unsigned short* __restrict__ Bbf,
    const float* __restrict__ ss, const float* __restrict__ wout,
    const unsigned short* __restrict__ Wt, unsigned short* __restrict__ Y, int nrows) {
    __shared__ short Xs[64][128];
    int tid = threadIdx.x;
    int row0 = blockIdx.x * 64;
    int wave = tid >> 6, lane = tid & 63;
    int m = lane & 15, quad = lane >> 4;
    float w1 = wout[0], w2 = wout[1];
    for (int u = tid; u < 1024; u += 256) {
        int r = u >> 4;
        int col0 = (u & 15) * 8;
        int gr = row0 + r;
        if (gr < nrows) {
#pragma unroll
            for (int hh = 0; hh < 2; ++hh) {
                int c = col0 + hh * 4;
                float4 fa = bf4tof4(*(const ushort4*)(Abf + (size_t)gr * 128 + c));
                float4 fb = bf4tof4(*(const ushort4*)(Bbf + (size_t)gr * 128 + c));
                float4 sa = *(const float4*)(ss + c);
                float4 ha = *(const float4*)(ss + 128 + c);
                float4 sb = *(const float4*)(ss + 256 + c);
                float4 hb = *(const float4*)(ss + 384 + c);
                ushort4 o;
                o.x = f2bf(w1 * fmaxf(fmaf(fa.x, sa.x, ha.x), 0.f) +
                           w2 * fmaxf(fmaf(fb.x, sb.x, hb.x), 0.f));
                o.y = f2bf(w1 * fmaxf(fmaf(fa.y, sa.y, ha.y), 0.f) +
                           w2 * fmaxf(fmaf(fb.y, sb.y, hb.y), 0.f));
                o.z = f2bf(w1 * fmaxf(fmaf(fa.z, sa.z, ha.z), 0.f) +
                           w2 * fmaxf(fmaf(fb.z, sb.z, hb.z), 0.f));
                o.w = f2bf(w1 * fmaxf(fmaf(fa.w, sa.w, ha.w), 0.f) +
                           w2 * fmaxf(fmaf(fb.w, sb.w, hb.w), 0.f));
                *(ushort4*)&Xs[r][c] = o;
            }
        } else {
            ushort4 z = {0, 0, 0, 0};
            *(ushort4*)&Xs[r][col0] = z;
            *(ushort4*)&Xs[r][col0 + 4] = z;
        }
    }
    __syncthreads();
    f32x4 acc[8];
#pragma unroll
    for (int i = 0; i < 8; ++i) acc[i] = (f32x4){0.f, 0.f, 0.f, 0.f};
#pragma unroll
    for (int kc = 0; kc < 4; ++kc) {
        bf16x8 a = *(const bf16x8*)&Xs[wave * 16 + m][kc * 32 + quad * 8];
#pragma unroll
        for (int ct = 0; ct < 8; ++ct) {
            const short* bp = (const short*)(Wt + ((size_t)(kc * 128 + ct * 16 + m) * 32) + quad * 8);
            bf16x8 b = *(const bf16x8*)bp;
            acc[ct] = __builtin_amdgcn_mfma_f32_16x16x32_bf16(a, b, acc[ct], 0, 0, 0);
        }
    }
#pragma unroll
    for (int ct = 0; ct < 8; ++ct) {
#pragma unroll
        for (int i = 0; i < 4; ++i) {
            int gr = row0 + wave * 16 + quad * 4 + i;
            if (gr < nrows) Y[(size_t)gr * 128 + ct * 16 + m] = f2bf(acc[ct][i]);
        }
    }
}

// ---------------- VALU fused GEMM (final 128->40) ----------------
template <int CG, int RPT>
__global__ __launch_bounds__(256) void gemm_fused_kernel(
    const unsigned short* __restrict__ Abf, const unsigned short* __restrict__ Bbf,
    const float* __restrict__ ss, const float* __restrict__ wout, const float* __restrict__ W,
    unsigned short* __restrict__ Y, int nrows, int fout, int ostride) {
    __shared__ float Ws[32][CG * 4];
    __shared__ float Xs[64][32];
    int tid = threadIdx.x;
    int row0 = blockIdx.x * 64;
    int cg = tid % CG;
    int rg = tid / CG;
    float w1 = wout[0], w2 = wout[1];
    float4 acc[RPT];
#pragma unroll
    for (int i = 0; i < RPT; ++i) acc[i] = make_float4(0.f, 0.f, 0.f, 0.f);
    for (int kc = 0; kc < 4; ++kc) {
        for (int i = tid; i < 32 * CG; i += 256) {
            int r = i / CG, c = i % CG;
            float4 w;
            if ((c * 4 + 3) < fout) {
                w = *(const float4*)(W + (size_t)(kc * 32 + r) * fout + c * 4);
            } else {
                float t0 = (c * 4 + 0) < fout ? W[(size_t)(kc * 32 + r) * fout + c * 4 + 0] : 0.f;
                float t1 = (c * 4 + 1) < fout ? W[(size_t)(kc * 32 + r) * fout + c * 4 + 1] : 0.f;
                float t2 = (c * 4 + 2) < fout ? W[(size_t)(kc * 32 + r) * fout + c * 4 + 2] : 0.f;
                float t3 = (c * 4 + 3) < fout ? W[(size_t)(kc * 32 + r) * fout + c * 4 + 3] : 0.f;
                w = make_float4(t0, t1, t2, t3);
            }
            *(float4*)&Ws[r][c * 4] = w;
        }
        for (int i = tid; i < 64 * 8; i += 256) {
            int r = i / 8, c = i % 8;
            int gr = row0 + r;
            int col0 = kc * 32 + c * 4;
            float4 v = make_float4(0.f, 0.f, 0.f, 0.f);
            if (gr < nrows) {
                float4 a = bf4tof4(*(const ushort4*)(Abf + (size_t)gr * DFEAT + col0));
                float4 b = bf4tof4(*(const ushort4*)(Bbf + (size_t)gr * DFEAT + col0));
                float4 scA = *(const float4*)(ss + col0);
                float4 shA = *(const float4*)(ss + DFEAT + col0);
                float4 scB = *(const float4*)(ss + 2 * DFEAT + col0);
                float4 shB = *(const float4*)(ss + 3 * DFEAT + col0);
                v.x = w1 * fmaxf(fmaf(a.x, scA.x, shA.x), 0.f) +
                      w2 * fmaxf(fmaf(b.x, scB.x, shB.x), 0.f);
                v.y = w1 * fmaxf(fmaf(a.y, scA.y, shA.y), 0.f) +
                      w2 * fmaxf(fmaf(b.y, scB.y, shB.y), 0.f);
                v.z = w1 * fmaxf(fmaf(a.z, scA.z, shA.z), 0.f) +
                      w2 * fmaxf(fmaf(b.z, scB.z, shB.z), 0.f);
                v.w = w1 * fmaxf(fmaf(a.w, scA.w, shA.w), 0.f) +
                      w2 * fmaxf(fmaf(b.w, scB.w, shB.w), 0.f);
            }
            *(float4*)&Xs[r][c * 4] = v;
        }
        __syncthreads();
#pragma unroll
        for (int k = 0; k < 32; ++k) {
            float4 w = *(float4*)&Ws[k][cg * 4];
#pragma unroll
            for (int i = 0; i < RPT; ++i) {
                float a = Xs[rg * RPT + i][k];
                acc[i].x = fmaf(a, w.x, acc[i].x);
                acc[i].y = fmaf(a, w.y, acc[i].y);
                acc[i].z = fmaf(a, w.z, acc[i].z);
                acc[i].w = fmaf(a, w.w, acc[i].w);
            }
        }
        __syncthreads();
    }
    if (cg * 4 < fout) {
#pragma unroll
        for (int i = 0; i < RPT; ++i) {
            int r = row0 + rg * RPT + i;
            if (r < nrows) {
                ushort4 o;
                o.x = f2bf(acc[i].x); o.y = f2bf(acc[i].y);
                o.z = f2bf(acc[i].z); o.w = f2bf(acc[i].w);
                *(ushort4*)(Y + (size_t)r * ostride + cg * 4) = o;
            }
        }
    }
}

// ---------------- BN statistics: 2-level atomicAdd ----------------
__global__ __launch_bounds__(256) void stats2_kernel(const unsigned short* __restrict__ A,
                                                     const unsigned short* __restrict__ B,
                                                     float* __restrict__ stats, int nrows) {
    __shared__ float red1[256];
    __shared__ float red2[256];
    int t = threadIdx.x;
    int col = t & 127;
    int rg = t >> 7;
    const unsigned short* src = (blockIdx.y == 0) ? A : B;
    float* st = stats + (size_t)blockIdx.y * 256;
    int r0 = blockIdx.x * 128 + rg * 64;
    int r1 = min(r0 + 64, nrows);
    float s = 0.f, s2 = 0.f;
    for (int r = r0; r < r1; ++r) {
        float v = bf2f(src[(size_t)r * DFEAT + col]);
        s += v;
        s2 = fmaf(v, v, s2);
    }
    red1[t] = s;
    red2[t] = s2;
    __syncthreads();
    if (t < 128) {
        atomicAdd(&st[col], red1[t] + red1[t + 128]);
        atomicAdd(&st[DFEAT + col], red2[t] + red2[t + 128]);
    }
}

// ---------------- BN scale/shift + gates; zeros stats for next layer ----------------
__global__ __launch_bounds__(128) void gate_prep_kernel(
    float* __restrict__ statsA, float* __restrict__ statsB,
    const unsigned short* __restrict__ preA, const unsigned short* __restrict__ preB,
    const float* __restrict__ gamma, const float* __restrict__ beta,
    const float* __restrict__ gwA, const float* __restrict__ gbA,
    const float* __restrict__ gwB, const float* __restrict__ gbB,
    float* __restrict__ ss, float* __restrict__ wout, int nrows) {
    __shared__ float red[128];
    __shared__ float dotA_s;
    int t = threadIdx.x;
    float invN = 1.f / (float)nrows;
    float meanA = statsA[t] * invN;
    float varA = statsA[DFEAT + t] * invN - meanA * meanA;
    float scA = gamma[t] * rsqrtf(varA + 1e-5f);
    float shA = beta[t] - meanA * scA;
    ss[t] = scA;
    ss[DFEAT + t] = shA;
    float meanB = statsB[t] * invN;
    float varB = statsB[DFEAT + t] * invN - meanB * meanB;
    float scB = gamma[t] * rsqrtf(varB + 1e-5f);
    float shB = beta[t] - meanB * scB;
    ss[2 * DFEAT + t] = scB;
    ss[3 * DFEAT + t] = shB;
    statsA[t] = 0.f;
    statsA[DFEAT + t] = 0.f;
    statsB[t] = 0.f;
    statsB[DFEAT + t] = 0.f;
    float av = fmaxf(fmaf(bf2f(preA[(size_t)(nrows - 1) * DFEAT + t]), scA, shA), 0.f);
    red[t] = av * gwA[t];
    __syncthreads();
    for (int s = 64; s > 0; s >>= 1) {
        if (t < s) red[t] += red[t + s];
        __syncthreads();
    }
    if (t == 0) dotA_s = red[0];
    __syncthreads();
    float bv = fmaxf(fmaf(bf2f(preB[(size_t)(nrows - 1) * DFEAT + t]), scB, shB), 0.f);
    red[t] = bv * gwB[t];
    __syncthreads();
    for (int s = 64; s > 0; s >>= 1) {
        if (t < s) red[t] += red[t + s];
        __syncthreads();
    }
    if (t == 0) {
        float s1 = 1.f / (1.f + expf(-(dotA_s + gbA[0])));
        float s2 = 1.f / (1.f + expf(-(red[0] + gbB[0])));
        float tt = s1 + s2;
        wout[0] = s1 / tt;
        wout[1] = s2 / tt;
    }
}

__global__ __launch_bounds__(64) void gate_final_kernel(
    const float* __restrict__ p1, const float* __restrict__ p2,
    const float* __restrict__ w1v, const float* __restrict__ b1,
    const float* __restrict__ w2v, const float* __restrict__ b2,
    float* __restrict__ wout, int nrows, int nclass) {
    __shared__ float red[64];
    __shared__ float dot1_s;
    int t = threadIdx.x;
    float v = (t < nclass) ? p1[(size_t)(nrows - 1) * nclass + t] * w1v[t] : 0.f;
    red[t] = v;
    __syncthreads();
    for (int s = 32; s > 0; s >>= 1) {
        if (t < s) red[t] += red[t + s];
        __syncthreads();
    }
    if (t == 0) dot1_s = red[0];
    __syncthreads();
    v = (t < nclass) ? p2[(size_t)(nrows - 1) * nclass + t] * w2v[t] : 0.f;
    red[t] = v;
    __syncthreads();
    for (int s = 32; s > 0; s >>= 1) {
        if (t < s) red[t] += red[t + s];
        __syncthreads();
    }
    if (t == 0) {
        float s1 = 1.f / (1.f + expf(-(dot1_s + b1[0])));
        float s2 = 1.f / (1.f + expf(-(red[0] + b2[0])));
        float tt = s1 + s2;
        wout[0] = s1 / tt;
        wout[1] = s2 / tt;
    }
}

__global__ __launch_bounds__(256) void mix_kernel(const float* __restrict__ p1,
                                                  const float* __restrict__ p2,
                                                  const float* __restrict__ wout,
                                                  float* __restrict__ o, int n4) {
    int idx = blockIdx.x * blockDim.x + threadIdx.x;
    if (idx >= n4) return;
    float w1 = wout[0], w2 = wout[1];
    float4 a = *(const float4*)(p1 + (size_t)idx * 4);
    float4 b = *(const float4*)(p2 + (size_t)idx * 4);
    float4 r = make_float4(w1 * a.x + w2 * b.x, w1 * a.y + w2 * b.y, w1 * a.z + w2 * b.z,
                           w1 * a.w + w2 * b.w);
    *(float4*)(o + (size_t)idx * 4) = r;
}

extern "C" void kernel_launch(void* const* d_in, const int* in_sizes, int n_in, void* d_out,
                              int out_size, void* d_ws, size_t ws_size, hipStream_t stream) {
    (void)n_in; (void)out_size; (void)ws_size;
    const int N = in_sizes[0] / DFEAT;        // 50000
    const int E = in_sizes[4] / 2;            // 800000
    const int NC = in_sizes[15];              // 40

    const float* x1a = (const float*)d_in[0];
    const float* x1b = (const float*)d_in[1];
    const float* x2a = (const float*)d_in[2];
    const float* x2b = (const float*)d_in[3];
    const int* ei1 = (const int*)d_in[4];
    const int* ei2 = (const int*)d_in[5];
    const float* Wi = (const float*)d_in[6];
    const float* bi = (const float*)d_in[7];
    const float* gi = (const float*)d_in[8];
    const float* bei = (const float*)d_in[9];
    const float* Wm = (const float*)d_in[10];
    const float* bm = (const float*)d_in[11];
    const float* gm = (const float*)d_in[12];
    const float* bem = (const float*)d_in[13];
    const float* Wf = (const float*)d_in[14];
    const float* bf = (const float*)d_in[15];
    const float* fc1w1_W = (const float*)d_in[16];
    const float* fc1w1_b = (const float*)d_in[17];
    const float* fc1w2_W = (const float*)d_in[18];
    const float* fc1w2_b = (const float*)d_in[19];
    const float* aws_w1_W = (const float*)d_in[20];
    const float* aws_w1_b = (const float*)d_in[21];
    const float* aws_w2_W = (const float*)d_in[22];
    const float* aws_w2_b = (const float*)d_in[23];
    const float* fcw1_W = (const float*)d_in[24];
    const float* fcw1_b = (const float*)d_in[25];
    const float* fcw2_W = (const float*)d_in[26];
    const float* fcw2_b = (const float*)d_in[27];

    char* ws = (char*)d_ws;
    size_t off = 0;
    auto alloc = [&](size_t bytes) -> char* {
        char* p = ws + off;
        off += (bytes + 255) & ~(size_t)255;
        return p;
    };
    unsigned short* A = (unsigned short*)alloc((size_t)N * DFEAT * 2);
    unsigned short* B = (unsigned short*)alloc((size_t)N * DFEAT * 2);
    unsigned short* H1 = (unsigned short*)alloc((size_t)N * DFEAT * 2);
    unsigned short* H2 = (unsigned short*)alloc((size_t)N * DFEAT * 2);
    int* rp1 = (int*)alloc((size_t)(N + 1) * 4);
    int* rp2 = (int*)alloc((size_t)(N + 1) * 4);
    int* cnt1 = (int*)alloc((size_t)N * 4);   // written densely by binhist
    int* cnt2 = (int*)alloc((size_t)N * 4);
    int* zb = (int*)alloc((size_t)(2 * N + 128) * 4);  // fl1|fl2|gcnt1|gcnt2 — one memset
    int* fl1 = zb;
    int* fl2 = zb + N;
    int* gcnt1 = zb + 2 * N;
    int* gcnt2 = zb + 2 * N + 64;
    float* dv1 = (float*)alloc((size_t)N * 4);
    float* dv2 = (float*)alloc((size_t)N * 4);
    int* cs1 = (int*)alloc((size_t)E * 4);
    int* cs2 = (int*)alloc((size_t)E * 4);
    // bucket geometry: nodes per bucket = 1024, nbk buckets (<=64 since N<=65536)
    int nbk = (N + 1023) >> 10;               // 49
    int scap = (((E / nbk) * 3) / 2 + 255) & ~255;  // ~1.5x mean bucket size
    int* stg1 = (int*)alloc((size_t)nbk * scap * 4);
    int* stg2 = (int*)alloc((size_t)nbk * scap * 4);
    unsigned short* Wt = (unsigned short*)alloc((size_t)2 * 16384 * 2);
    float* stats = (float*)alloc(2048);
    float* statsA = stats;
    float* statsB = stats + 256;
    float* ssbuf = (float*)alloc(2048);
    float* wout = (float*)alloc(256);
    int nb = (N + 2047) / 2048;  // 25
    int* bsums = (int*)alloc((size_t)2 * nb * 4);

    const int* src1 = ei1;
    const int* dst1 = ei1 + E;
    const int* src2 = ei2;
    const int* dst2 = ei2 + E;

    int gemmbl = (N + 63) / 64;
    dim3 bingrid((E + EPB - 1) / EPB, 2);
    dim3 bkgrid(nbk, 2);
    dim3 agggrid((N + 3) / 4, 2);
    dim3 statgrid((N + 127) / 128, 2);
    dim3 scangrid(nb, 2);
    dim3 l1grid(gemmbl, 4);
    dim3 prepgrid(64, 2);

    // ---- CSR build (2-level bucket sort) + weight prep ----
    hipMemsetAsync(zb, 0, (size_t)(2 * N + 128) * 4, stream);
    binA_kernel<<<bingrid, 256, 0, stream>>>(src1, dst1, src2, dst2, stg1, stg2, gcnt1, gcnt2,
                                             E, nbk, scap);
    prepW_kernel<<<prepgrid, 256, 0, stream>>>(Wm, Wt);
    binhist_kernel<<<bkgrid, 256, 0, stream>>>(stg1, stg2, gcnt1, gcnt2, cnt1, cnt2, N, scap);
    blocksum_kernel<<<scangrid, 256, 0, stream>>>(cnt1, cnt2, bsums, N, nb);
    scansums_kernel<<<1, 64, 0, stream>>>(bsums, nb, rp1, rp2, N, E, stats);
    writerp_kernel<<<scangrid, 256, 0, stream>>>(cnt1, cnt2, bsums, rp1, rp2, dv1, dv2, N, nb);
    binB_kernel<<<bkgrid, 256, 0, stream>>>(stg1, stg2, gcnt1, gcnt2, rp1, rp2, fl1, fl2,
                                            cs1, cs2, scap);

    // ---- Layer 1 ----
    gemm_l1_kernel<<<l1grid, 256, 0, stream>>>(x1a, x1b, x2a, x2b, Wi, H1, H2, N);
    dualagg_kernel<32, unsigned short><<<agggrid, 256, 0, stream>>>(
        H1, H2, rp1, cs1, dv1, rp2, cs2, dv2, bi, A, B, N);
    stats2_kernel<<<statgrid, 256, 0, stream>>>(A, B, stats, N);
    gate_prep_kernel<<<1, 128, 0, stream>>>(statsA, statsB, A, B, gi, bei, fc1w1_W, fc1w1_b,
                                            fc1w2_W, fc1w2_b, ssbuf, wout, N);

    // ---- Middle layer 0 (MFMA fused GEMM) ----
    gemm_mfma_kernel<<<gemmbl, 256, 0, stream>>>(A, B, ssbuf, wout, Wt, H1, N);
    dualagg_kernel<32, unsigned short><<<agggrid, 256, 0, stream>>>(
        H1, H1, rp1, cs1, dv1, rp2, cs2, dv2, bm, A, B, N);
    stats2_kernel<<<statgrid, 256, 0, stream>>>(A, B, stats, N);
    gate_prep_kernel<<<1, 128, 0, stream>>>(statsA, statsB, A, B, gm, bem, aws_w1_W, aws_w1_b,
                                            aws_w2_W, aws_w2_b, ssbuf, wout, N);

    // ---- Middle layer 1 ----
    gemm_mfma_kernel<<<gemmbl, 256, 0, stream>>>(A, B, ssbuf, wout, Wt + 16384, H1, N);
    dualagg_kernel<32, unsigned short><<<agggrid, 256, 0, stream>>>(
        H1, H1, rp1, cs1, dv1, rp2, cs2, dv2, bm + 128, A, B, N);
    stats2_kernel<<<statgrid, 256, 0, stream>>>(A, B, stats, N);
    gate_prep_kernel<<<1, 128, 0, stream>>>(statsA, statsB, A, B, gm + 128, bem + 128,
                                            aws_w1_W + 128, aws_w1_b + 1, aws_w2_W + 128,
                                            aws_w2_b + 1, ssbuf, wout, N);

    // ---- Final layer ----
    float* out0 = (float*)d_out;
    float* p1 = out0 + (size_t)N * NC;
    float* p2 = out0 + (size_t)2 * N * NC;
    gemm_fused_kernel<16, 4><<<gemmbl, 256, 0, stream>>>(A, B, ssbuf, wout, Wf, H2, N, NC, NC);
    dualagg_kernel<10, float><<<agggrid, 256, 0, stream>>>(H2, H2, rp1, cs1, dv1, rp2, cs2, dv2,
                                                           bf, p1, p2, N);
    gate_final_kernel<<<1, 64, 0, stream>>>(p1, p2, fcw1_W, fcw1_b, fcw2_W, fcw2_b, wout, N, NC);
    mix_kernel<<<(N * NC / 4 + 255) / 256, 256, 0, stream>>>(p1, p2, wout, out0, N * NC / 4);
}

// Round 2
// 786.290 us; speedup vs baseline: 1.1293x; 1.1293x over previous
//
#include <hip/hip_runtime.h>

// CLAGCN forward on MI355X.
// R1: stats 2-level. R2: multi-block scan. R3: bf16 staging + dual agg +
// fused combine. R4: revert stats to atomicAdd. R5: wave/node agg, bf16 A/B,
// fewer dispatches. R6: fill payload 4B; middle GEMMs -> MFMA bf16.
// R7 (FAILED): LDS-buffered bucket sort — fixed write amplification (112->9MB)
//     but barrier/flush latency chain at 15% occupancy made binA 158us.
// R8: destination-range-partitioned count+fill. 8 node ranges (one per XCD
//     via blockIdx%8 round-robin) x 128 edge slices. Each block streams its
//     slice sequentially (edge arrays are Infinity-Cache resident; 8x nominal
//     re-read is absorbed) and handles only dsts in its range:
//     - countR: 25KB LDS histogram -> dense coalesced atomic merge
//       (kills 1.6M random global atomics of old count_kernel);
//     - fillR: scatter confined to a ~400KB XCD-local cs window -> lines go
//       fully dirty in ONE L2 before write-back -> dense HBM writes (~7MB
//       vs 112MB). No barriers, 2048 independent blocks.

#define DFEAT 128

typedef __attribute__((ext_vector_type(8))) short bf16x8;
typedef __attribute__((ext_vector_type(4))) float f32x4;

__device__ __forceinline__ unsigned short f2bf(float f) {
    unsigned u = __float_as_uint(f);
    u += 0x7fffu + ((u >> 16) & 1u);
    return (unsigned short)(u >> 16);
}
__device__ __forceinline__ float bf2f(unsigned short u) {
    return __uint_as_float((unsigned)u << 16);
}
__device__ __forceinline__ float4 bf4tof4(ushort4 u) {
    return make_float4(__uint_as_float((unsigned)u.x << 16),
                       __uint_as_float((unsigned)u.y << 16),
                       __uint_as_float((unsigned)u.z << 16),
                       __uint_as_float((unsigned)u.w << 16));
}

// ---------------- ranged CSR build ----------------
constexpr int RANGES = 8;     // = XCD count; blockIdx.x & 7 -> XCD (round-robin)
constexpr int SLICES = 128;   // edge-stream slices per range
constexpr int MAXRSZ = 6400;  // >= ceil(N/RANGES); N=50000 -> 6250

__global__ __launch_bounds__(256) void countR_kernel(
    const int* __restrict__ dst1, const int* __restrict__ dst2,
    int* __restrict__ cnt1, int* __restrict__ cnt2, int n, int E, int rsz) {
    const int* dst = blockIdx.y ? dst2 : dst1;
    int* cnt = blockIdx.y ? cnt2 : cnt1;
    int range = blockIdx.x & (RANGES - 1);
    int slice = blockIdx.x >> 3;
    int r0 = range * rsz;
    int rn = min(rsz, n - r0);
    if (rn <= 0) return;
    __shared__ int hist[MAXRSZ];
    int t = threadIdx.x;
    for (int i = t; i < rn; i += 256) hist[i] = 0;
    __syncthreads();
    int es = (E + SLICES - 1) / SLICES;
    int e0 = slice * es;
    int e1 = min(e0 + es, E);
    for (int i = e0 + t; i < e1; i += 256) {
        unsigned d = (unsigned)(dst[i] - r0);
        if (d < (unsigned)rn) atomicAdd(&hist[d], 1);
    }
    __syncthreads();
    for (int i = t; i < rn; i += 256) {
        int v = hist[i];
        if (v) atomicAdd(&cnt[r0 + i], v);
    }
}

__global__ __launch_bounds__(256) void fillR_kernel(
    const int* __restrict__ src1, const int* __restrict__ dst1,
    const int* __restrict__ src2, const int* __restrict__ dst2,
    const int* __restrict__ rp1, const int* __restrict__ rp2,
    int* __restrict__ fl1, int* __restrict__ fl2,
    int* __restrict__ cs1, int* __restrict__ cs2, int n, int E, int rsz) {
    const int *src, *dst, *rp;
    int *fl, *cs;
    if (blockIdx.y == 0) { src = src1; dst = dst1; rp = rp1; fl = fl1; cs = cs1; }
    else                 { src = src2; dst = dst2; rp = rp2; fl = fl2; cs = cs2; }
    int range = blockIdx.x & (RANGES - 1);
    int slice = blockIdx.x >> 3;
    int r0 = range * rsz;
    int rn = min(rsz, n - r0);
    if (rn <= 0) return;
    int es = (E + SLICES - 1) / SLICES;
    int e0 = slice * es;
    int e1 = min(e0 + es, E);
    for (int i = e0 + (int)threadIdx.x; i < e1; i += 256) {
        int d = dst[i];
        if ((unsigned)(d - r0) < (unsigned)rn) {
            int pos = rp[d] + atomicAdd(&fl[d], 1);
            cs[pos] = src[i];
        }
    }
}

// ---------------- CSR scan (unchanged) ----------------
__global__ __launch_bounds__(256) void blocksum_kernel(const int* __restrict__ c1,
                                                       const int* __restrict__ c2,
                                                       int* __restrict__ bs, int n, int nb) {
    const int* c = blockIdx.y ? c2 : c1;
    int* out = bs + (size_t)blockIdx.y * nb;
    int t = threadIdx.x;
    int base = blockIdx.x * 2048 + t * 8;
    int s = 0;
#pragma unroll
    for (int i = 0; i < 8; ++i) {
        int idx = base + i;
        if (idx < n) s += c[idx];
    }
    __shared__ int red[256];
    red[t] = s;
    __syncthreads();
    for (int o = 128; o > 0; o >>= 1) {
        if (t < o) red[t] += red[t + o];
        __syncthreads();
    }
    if (t == 0) out[blockIdx.x] = red[0];
}

__global__ void scansums_kernel(int* __restrict__ bs, int nb, int* __restrict__ rp1,
                                int* __restrict__ rp2, int n, int E, float* __restrict__ stats) {
    int t = threadIdx.x;  // 64 threads
    if (t < 2) {
        int* b = bs + (size_t)t * nb;
        int run = 0;
        for (int i = 0; i < nb; ++i) {
            int v = b[i];
            b[i] = run;
            run += v;
        }
        (t ? rp2 : rp1)[n] = E;
    }
    for (int i = t; i < 512; i += 64) stats[i] = 0.f;
}

__global__ __launch_bounds__(256) void writerp_kernel(const int* __restrict__ c1,
                                                      const int* __restrict__ c2,
                                                      const int* __restrict__ bs,
                                                      int* __restrict__ rp1, int* __restrict__ rp2,
                                                      float* __restrict__ dv1,
                                                      float* __restrict__ dv2, int n, int nb) {
    const int* c = blockIdx.y ? c2 : c1;
    int* rp = blockIdx.y ? rp2 : rp1;
    float* dv = blockIdx.y ? dv2 : dv1;
    int boff = bs[(size_t)blockIdx.y * nb + blockIdx.x];
    int t = threadIdx.x;
    int base = blockIdx.x * 2048 + t * 8;
    int v[8];
    int s = 0;
#pragma unroll
    for (int i = 0; i < 8; ++i) {
        int idx = base + i;
        v[i] = (idx < n) ? c[idx] : 0;
        s += v[i];
    }
    __shared__ int red[256];
    red[t] = s;
    __syncthreads();
    for (int o = 1; o < 256; o <<= 1) {
        int x = (t >= o) ? red[t - o] : 0;
        __syncthreads();
        red[t] += x;
        __syncthreads();
    }
    int run = boff + red[t] - s;
#pragma unroll
    for (int i = 0; i < 8; ++i) {
        int idx = base + i;
        if (idx < n) {
            rp[idx] = run;
            dv[idx] = rsqrtf((float)(v[i] + 1));  // +1 self-loop
            run += v[i];
        }
    }
}

// ---------------- dual aggregation: one wave per node ----------------
template <int FV, typename OutT>
__global__ __launch_bounds__(256) void dualagg_kernel(
    const unsigned short* __restrict__ h1, const unsigned short* __restrict__ h2,
    const int* __restrict__ rp1, const int* __restrict__ cs1, const float* __restrict__ dv1,
    const int* __restrict__ rp2, const int* __restrict__ cs2, const float* __restrict__ dv2,
    const float* __restrict__ bias, OutT* __restrict__ o1, OutT* __restrict__ o2, int n) {
    constexpr int COLS = FV * 4;
    const unsigned short* h;
    const int *rp, *cs;
    const float* dv;
    OutT* out;
    if (blockIdx.y == 0) { h = h1; rp = rp1; cs = cs1; dv = dv1; out = o1; }
    else                 { h = h2; rp = rp2; cs = cs2; dv = dv2; out = o2; }
    int wid = blockIdx.x * 4 + (threadIdx.x >> 6);
    if (wid >= n) return;
    int lane = threadIdx.x & 63;
    int half = lane >> 5;
    int l = lane & 31;
    bool act = (l < FV);
    float dn = dv[wid];
    float4 acc = make_float4(0.f, 0.f, 0.f, 0.f);
    int e0 = rp[wid], e1 = rp[wid + 1];
    int e = e0 + half;
    for (; e + 6 < e1; e += 8) {
        int sa = cs[e], sb = cs[e + 2], sc = cs[e + 4], sd = cs[e + 6];
        float wa = dv[sa] * dn, wb = dv[sb] * dn, wc = dv[sc] * dn, wd = dv[sd] * dn;
        if (act) {
            float4 ha = bf4tof4(((const ushort4*)(h + (size_t)sa * COLS))[l]);
            float4 hb = bf4tof4(((const ushort4*)(h + (size_t)sb * COLS))[l]);
            float4 hc = bf4tof4(((const ushort4*)(h + (size_t)sc * COLS))[l]);
            float4 hd = bf4tof4(((const ushort4*)(h + (size_t)sd * COLS))[l]);
            acc.x = fmaf(wa, ha.x, acc.x); acc.y = fmaf(wa, ha.y, acc.y);
            acc.z = fmaf(wa, ha.z, acc.z); acc.w = fmaf(wa, ha.w, acc.w);
            acc.x = fmaf(wb, hb.x, acc.x); acc.y = fmaf(wb, hb.y, acc.y);
            acc.z = fmaf(wb, hb.z, acc.z); acc.w = fmaf(wb, hb.w, acc.w);
            acc.x = fmaf(wc, hc.x, acc.x); acc.y = fmaf(wc, hc.y, acc.y);
            acc.z = fmaf(wc, hc.z, acc.z); acc.w = fmaf(wc, hc.w, acc.w);
            acc.x = fmaf(wd, hd.x, acc.x); acc.y = fmaf(wd, hd.y, acc.y);
            acc.z = fmaf(wd, hd.z, acc.z); acc.w = fmaf(wd, hd.w, acc.w);
        }
    }
    for (; e < e1; e += 2) {
        int sa = cs[e];
        float wa = dv[sa] * dn;
        if (act) {
            float4 ha = bf4tof4(((const ushort4*)(h + (size_t)sa * COLS))[l]);
            acc.x = fmaf(wa, ha.x, acc.x); acc.y = fmaf(wa, ha.y, acc.y);
            acc.z = fmaf(wa, ha.z, acc.z); acc.w = fmaf(wa, ha.w, acc.w);
        }
    }
    acc.x += __shfl_xor(acc.x, 32);
    acc.y += __shfl_xor(acc.y, 32);
    acc.z += __shfl_xor(acc.z, 32);
    acc.w += __shfl_xor(acc.w, 32);
    if (half == 0 && act) {
        float w = dn * dn;  // self-loop norm
        float4 hv = bf4tof4(((const ushort4*)(h + (size_t)wid * COLS))[l]);
        acc.x = fmaf(w, hv.x, acc.x); acc.y = fmaf(w, hv.y, acc.y);
        acc.z = fmaf(w, hv.z, acc.z); acc.w = fmaf(w, hv.w, acc.w);
        float4 b = ((const float4*)bias)[l];
        acc.x += b.x; acc.y += b.y; acc.z += b.z; acc.w += b.w;
        if constexpr (sizeof(OutT) == 4) {
            ((float4*)((float*)out + (size_t)wid * COLS))[l] = acc;
        } else {
            ushort4 o;
            o.x = f2bf(acc.x); o.y = f2bf(acc.y); o.z = f2bf(acc.z); o.w = f2bf(acc.w);
            ((ushort4*)((unsigned short*)out + (size_t)wid * COLS))[l] = o;
        }
    }
}

// ---------------- Layer-1 quad GEMM ----------------
__global__ __launch_bounds__(256) void gemm_l1_kernel(
    const float* __restrict__ x1a, const float* __restrict__ x1b, const float* __restrict__ x2a,
    const float* __restrict__ x2b, const float* __restrict__ Wi, unsigned short* __restrict__ H1,
    unsigned short* __restrict__ H2, int nrows) {
    constexpr int CG = 16;
    const float* X = (blockIdx.y == 0) ? x1a : (blockIdx.y == 1) ? x1b
                     : (blockIdx.y == 2) ? x2a : x2b;
    const float* W = Wi + (blockIdx.y & 1) * 128 * 64;
    unsigned short* Y = (blockIdx.y < 2) ? H1 : H2;
    int ocol = (int)(blockIdx.y & 1) * 64;
    __shared__ float Ws[32][64];
    __shared__ float Xs[64][32];
    int tid = threadIdx.x;
    int row0 = blockIdx.x * 64;
    int cg = tid % CG;
    int rg = tid / CG;
    float4 acc[4];
#pragma unroll
    for (int i = 0; i < 4; ++i) acc[i] = make_float4(0.f, 0.f, 0.f, 0.f);
    for (int kc = 0; kc < 4; ++kc) {
        for (int i = tid; i < 32 * CG; i += 256) {
            int r = i / CG, c = i % CG;
            *(float4*)&Ws[r][c * 4] = *(const float4*)(W + (size_t)(kc * 32 + r) * 64 + c * 4);
        }
        for (int i = tid; i < 64 * 8; i += 256) {
            int r = i / 8, c = i % 8;
            int gr = row0 + r;
            float4 v = make_float4(0.f, 0.f, 0.f, 0.f);
            if (gr < nrows) v = *(const float4*)(X + (size_t)gr * DFEAT + kc * 32 + c * 4);
            *(float4*)&Xs[r][c * 4] = v;
        }
        __syncthreads();
#pragma unroll
        for (int k = 0; k < 32; ++k) {
            float4 w = *(float4*)&Ws[k][cg * 4];
#pragma unroll
            for (int i = 0; i < 4; ++i) {
                float a = Xs[rg * 4 + i][k];
                acc[i].x = fmaf(a, w.x, acc[i].x);
                acc[i].y = fmaf(a, w.y, acc[i].y);
                acc[i].z = fmaf(a, w.z, acc[i].z);
                acc[i].w = fmaf(a, w.w, acc[i].w);
            }
        }
        __syncthreads();
    }
#pragma unroll
    for (int i = 0; i < 4; ++i) {
        int r = row0 + rg * 4 + i;
        if (r < nrows) {
            ushort4 o;
            o.x = f2bf(acc[i].x); o.y = f2bf(acc[i].y);
            o.z = f2bf(acc[i].z); o.w = f2bf(acc[i].w);
            *(ushort4*)(Y + (size_t)r * DFEAT + ocol + cg * 4) = o;
        }
    }
}

// ---------------- prepW: Wm (2x128x128 fp32) -> bf16 transposed [l][kc][col][kk] ----------------
__global__ __launch_bounds__(256) void prepW_kernel(const float* __restrict__ Wm,
                                                    unsigned short* __restrict__ Wt) {
    int o = blockIdx.x * 256 + threadIdx.x;  // 16384 per layer
    int l = blockIdx.y;
    int kk = o & 31;
    int col = (o >> 5) & 127;
    int kc = o >> 12;
    int k = kc * 32 + kk;
    Wt[(size_t)l * 16384 + o] = f2bf(Wm[(size_t)l * 16384 + (size_t)k * 128 + col]);
}

// ---------------- MFMA fused GEMM (128->128): x = w1*relu(bn(A)) + w2*relu(bn(B)) ----------------
__global__ __launch_bounds__(256) void gemm_mfma_kernel(
    const unsigned short* __restrict__ Abf, const unsigned short* __restrict__ Bbf,
    const float* __restrict__ ss, const float* __restrict__ wout,
    const unsigned short* __restrict__ Wt, unsigned short* __restrict__ Y, int nrows) {
    __shared__ short Xs[64][128];
    int tid = threadIdx.x;
    int row0 = blockIdx.x * 64;
    int wave = tid >> 6, lane = tid & 63;
    int m = lane & 15, quad = lane >> 4;
    float w1 = wout[0], w2 = wout[1];
    for (int u = tid; u < 1024; u += 256) {
        int r = u >> 4;
        int col0 = (u & 15) * 8;
        int gr = row0 + r;
        if (gr < nrows) {
#pragma unroll
            for (int hh = 0; hh < 2; ++hh) {
                int c = col0 + hh * 4;
                float4 fa = bf4tof4(*(const ushort4*)(Abf + (size_t)gr * 128 + c));
                float4 fb = bf4tof4(*(const ushort4*)(Bbf + (size_t)gr * 128 + c));
                float4 sa = *(const float4*)(ss + c);
                float4 ha = *(const float4*)(ss + 128 + c);
                float4 sb = *(const float4*)(ss + 256 + c);
                float4 hb = *(const float4*)(ss + 384 + c);
                ushort4 o;
                o.x = f2bf(w1 * fmaxf(fmaf(fa.x, sa.x, ha.x), 0.f) +
                           w2 * fmaxf(fmaf(fb.x, sb.x, hb.x), 0.f));
                o.y = f2bf(w1 * fmaxf(fmaf(fa.y, sa.y, ha.y), 0.f) +
                           w2 * fmaxf(fmaf(fb.y, sb.y, hb.y), 0.f));
                o.z = f2bf(w1 * fmaxf(fmaf(fa.z, sa.z, ha.z), 0.f) +
                           w2 * fmaxf(fmaf(fb.z, sb.z, hb.z), 0.f));
                o.w = f2bf(w1 * fmaxf(fmaf(fa.w, sa.w, ha.w), 0.f) +
                           w2 * fmaxf(fmaf(fb.w, sb.w, hb.w), 0.f));
                *(ushort4*)&Xs[r][c] = o;
            }
        } else {
            ushort4 z = {0, 0, 0, 0};
            *(ushort4*)&Xs[r][col0] = z;
            *(ushort4*)&Xs[r][col0 + 4] = z;
        }
    }
    __syncthreads();
    f32x4 acc[8];
#pragma unroll
    for (int i = 0; i < 8; ++i) acc[i] = (f32x4){0.f, 0.f, 0.f, 0.f};
#pragma unroll
    for (int kc = 0; kc < 4; ++kc) {
        bf16x8 a = *(const bf16x8*)&Xs[wave * 16 + m][kc * 32 + quad * 8];
#pragma unroll
        for (int ct = 0; ct < 8; ++ct) {
            const short* bp = (const short*)(Wt + ((size_t)(kc * 128 + ct * 16 + m) * 32) + quad * 8);
            bf16x8 b = *(const bf16x8*)bp;
            acc[ct] = __builtin_amdgcn_mfma_f32_16x16x32_bf16(a, b, acc[ct], 0, 0, 0);
        }
    }
#pragma unroll
    for (int ct = 0; ct < 8; ++ct) {
#pragma unroll
        for (int i = 0; i < 4; ++i) {
            int gr = row0 + wave * 16 + quad * 4 + i;
            if (gr < nrows) Y[(size_t)gr * 128 + ct * 16 + m] = f2bf(acc[ct][i]);
        }
    }
}

// ---------------- VALU fused GEMM (final 128->40) ----------------
template <int CG, int RPT>
__global__ __launch_bounds__(256) void gemm_fused_kernel(
    const unsigned short* __restrict__ Abf, const unsigned short* __restrict__ Bbf,
    const float* __restrict__ ss, const float* __restrict__ wout, const float* __restrict__ W,
    unsigned short* __restrict__ Y, int nrows, int fout, int ostride) {
    __shared__ float Ws[32][CG * 4];
    __shared__ float Xs[64][32];
    int tid = threadIdx.x;
    int row0 = blockIdx.x * 64;
    int cg = tid % CG;
    int rg = tid / CG;
    float w1 = wout[0], w2 = wout[1];
    float4 acc[RPT];
#pragma unroll
    for (int i = 0; i < RPT; ++i) acc[i] = make_float4(0.f, 0.f, 0.f, 0.f);
    for (int kc = 0; kc < 4; ++kc) {
        for (int i = tid; i < 32 * CG; i += 256) {
            int r = i / CG, c = i % CG;
            float4 w;
            if ((c * 4 + 3) < fout) {
                w = *(const float4*)(W + (size_t)(kc * 32 + r) * fout + c * 4);
            } else {
                float t0 = (c * 4 + 0) < fout ? W[(size_t)(kc * 32 + r) * fout + c * 4 + 0] : 0.f;
                float t1 = (c * 4 + 1) < fout ? W[(size_t)(kc * 32 + r) * fout + c * 4 + 1] : 0.f;
                float t2 = (c * 4 + 2) < fout ? W[(size_t)(kc * 32 + r) * fout + c * 4 + 2] : 0.f;
                float t3 = (c * 4 + 3) < fout ? W[(size_t)(kc * 32 + r) * fout + c * 4 + 3] : 0.f;
                w = make_float4(t0, t1, t2, t3);
            }
            *(float4*)&Ws[r][c * 4] = w;
        }
        for (int i = tid; i < 64 * 8; i += 256) {
            int r = i / 8, c = i % 8;
            int gr = row0 + r;
            int col0 = kc * 32 + c * 4;
            float4 v = make_float4(0.f, 0.f, 0.f, 0.f);
            if (gr < nrows) {
                float4 a = bf4tof4(*(const ushort4*)(Abf + (size_t)gr * DFEAT + col0));
                float4 b = bf4tof4(*(const ushort4*)(Bbf + (size_t)gr * DFEAT + col0));
                float4 scA = *(const float4*)(ss + col0);
                float4 shA = *(const float4*)(ss + DFEAT + col0);
                float4 scB = *(const float4*)(ss + 2 * DFEAT + col0);
                float4 shB = *(const float4*)(ss + 3 * DFEAT + col0);
                v.x = w1 * fmaxf(fmaf(a.x, scA.x, shA.x), 0.f) +
                      w2 * fmaxf(fmaf(b.x, scB.x, shB.x), 0.f);
                v.y = w1 * fmaxf(fmaf(a.y, scA.y, shA.y), 0.f) +
                      w2 * fmaxf(fmaf(b.y, scB.y, shB.y), 0.f);
                v.z = w1 * fmaxf(fmaf(a.z, scA.z, shA.z), 0.f) +
                      w2 * fmaxf(fmaf(b.z, scB.z, shB.z), 0.f);
                v.w = w1 * fmaxf(fmaf(a.w, scA.w, shA.w), 0.f) +
                      w2 * fmaxf(fmaf(b.w, scB.w, shB.w), 0.f);
            }
            *(float4*)&Xs[r][c * 4] = v;
        }
        __syncthreads();
#pragma unroll
        for (int k = 0; k < 32; ++k) {
            float4 w = *(float4*)&Ws[k][cg * 4];
#pragma unroll
            for (int i = 0; i < RPT; ++i) {
                float a = Xs[rg * RPT + i][k];
                acc[i].x = fmaf(a, w.x, acc[i].x);
                acc[i].y = fmaf(a, w.y, acc[i].y);
                acc[i].z = fmaf(a, w.z, acc[i].z);
                acc[i].w = fmaf(a, w.w, acc[i].w);
            }
        }
        __syncthreads();
    }
    if (cg * 4 < fout) {
#pragma unroll
        for (int i = 0; i < RPT; ++i) {
            int r = row0 + rg * RPT + i;
            if (r < nrows) {
                ushort4 o;
                o.x = f2bf(acc[i].x); o.y = f2bf(acc[i].y);
                o.z = f2bf(acc[i].z); o.w = f2bf(acc[i].w);
                *(ushort4*)(Y + (size_t)r * ostride + cg * 4) = o;
            }
        }
    }
}

// ---------------- BN statistics: 2-level atomicAdd ----------------
__global__ __launch_bounds__(256) void stats2_kernel(const unsigned short* __restrict__ A,
                                                     const unsigned short* __restrict__ B,
                                                     float* __restrict__ stats, int nrows) {
    __shared__ float red1[256];
    __shared__ float red2[256];
    int t = threadIdx.x;
    int col = t & 127;
    int rg = t >> 7;
    const unsigned short* src = (blockIdx.y == 0) ? A : B;
    float* st = stats + (size_t)blockIdx.y * 256;
    int r0 = blockIdx.x * 128 + rg * 64;
    int r1 = min(r0 + 64, nrows);
    float s = 0.f, s2 = 0.f;
    for (int r = r0; r < r1; ++r) {
        float v = bf2f(src[(size_t)r * DFEAT + col]);
        s += v;
        s2 = fmaf(v, v, s2);
    }
    red1[t] = s;
    red2[t] = s2;
    __syncthreads();
    if (t < 128) {
        atomicAdd(&st[col], red1[t] + red1[t + 128]);
        atomicAdd(&st[DFEAT + col], red2[t] + red2[t + 128]);
    }
}

// ---------------- BN scale/shift + gates; zeros stats for next layer ----------------
__global__ __launch_bounds__(128) void gate_prep_kernel(
    float* __restrict__ statsA, float* __restrict__ statsB,
    const unsigned short* __restrict__ preA, const unsigned short* __restrict__ preB,
    const float* __restrict__ gamma, const float* __restrict__ beta,
    const float* __restrict__ gwA, const float* __restrict__ gbA,
    const float* __restrict__ gwB, const float* __restrict__ gbB,
    float* __restrict__ ss, float* __restrict__ wout, int nrows) {
    __shared__ float red[128];
    __shared__ float dotA_s;
    int t = threadIdx.x;
    float invN = 1.f / (float)nrows;
    float meanA = statsA[t] * invN;
    float varA = statsA[DFEAT + t] * invN - meanA * meanA;
    float scA = gamma[t] * rsqrtf(varA + 1e-5f);
    float shA = beta[t] - meanA * scA;
    ss[t] = scA;
    ss[DFEAT + t] = shA;
    float meanB = statsB[t] * invN;
    float varB = statsB[DFEAT + t] * invN - meanB * meanB;
    float scB = gamma[t] * rsqrtf(varB + 1e-5f);
    float shB = beta[t] - meanB * scB;
    ss[2 * DFEAT + t] = scB;
    ss[3 * DFEAT + t] = shB;
    statsA[t] = 0.f;
    statsA[DFEAT + t] = 0.f;
    statsB[t] = 0.f;
    statsB[DFEAT + t] = 0.f;
    float av = fmaxf(fmaf(bf2f(preA[(size_t)(nrows - 1) * DFEAT + t]), scA, shA), 0.f);
    red[t] = av * gwA[t];
    __syncthreads();
    for (int s = 64; s > 0; s >>= 1) {
        if (t < s) red[t] += red[t + s];
        __syncthreads();
    }
    if (t == 0) dotA_s = red[0];
    __syncthreads();
    float bv = fmaxf(fmaf(bf2f(preB[(size_t)(nrows - 1) * DFEAT + t]), scB, shB), 0.f);
    red[t] = bv * gwB[t];
    __syncthreads();
    for (int s = 64; s > 0; s >>= 1) {
        if (t < s) red[t] += red[t + s];
        __syncthreads();
    }
    if (t == 0) {
        float s1 = 1.f / (1.f + expf(-(dotA_s + gbA[0])));
        float s2 = 1.f / (1.f + expf(-(red[0] + gbB[0])));
        float tt = s1 + s2;
        wout[0] = s1 / tt;
        wout[1] = s2 / tt;
    }
}

__global__ __launch_bounds__(64) void gate_final_kernel(
    const float* __restrict__ p1, const float* __restrict__ p2,
    const float* __restrict__ w1v, const float* __restrict__ b1,
    const float* __restrict__ w2v, const float* __restrict__ b2,
    float* __restrict__ wout, int nrows, int nclass) {
    __shared__ float red[64];
    __shared__ float dot1_s;
    int t = threadIdx.x;
    float v = (t < nclass) ? p1[(size_t)(nrows - 1) * nclass + t] * w1v[t] : 0.f;
    red[t] = v;
    __syncthreads();
    for (int s = 32; s > 0; s >>= 1) {
        if (t < s) red[t] += red[t + s];
        __syncthreads();
    }
    if (t == 0) dot1_s = red[0];
    __syncthreads();
    v = (t < nclass) ? p2[(size_t)(nrows - 1) * nclass + t] * w2v[t] : 0.f;
    red[t] = v;
    __syncthreads();
    for (int s = 32; s > 0; s >>= 1) {
        if (t < s) red[t] += red[t + s];
        __syncthreads();
    }
    if (t == 0) {
        float s1 = 1.f / (1.f + expf(-(dot1_s + b1[0])));
        float s2 = 1.f / (1.f + expf(-(red[0] + b2[0])));
        float tt = s1 + s2;
        wout[0] = s1 / tt;
        wout[1] = s2 / tt;
    }
}

__global__ __launch_bounds__(256) void mix_kernel(const float* __restrict__ p1,
                                                  const float* __restrict__ p2,
                                                  const float* __restrict__ wout,
                                                  float* __restrict__ o, int n4) {
    int idx = blockIdx.x * blockDim.x + threadIdx.x;
    if (idx >= n4) return;
    float w1 = wout[0], w2 = wout[1];
    float4 a = *(const float4*)(p1 + (size_t)idx * 4);
    float4 b = *(const float4*)(p2 + (size_t)idx * 4);
    float4 r = make_float4(w1 * a.x + w2 * b.x, w1 * a.y + w2 * b.y, w1 * a.z + w2 * b.z,
                           w1 * a.w + w2 * b.w);
    *(float4*)(o + (size_t)idx * 4) = r;
}

extern "C" void kernel_launch(void* const* d_in, const int* in_sizes, int n_in, void* d_out,
                              int out_size, void* d_ws, size_t ws_size, hipStream_t stream) {
    (void)n_in; (void)out_size; (void)ws_size;
    const int N = in_sizes[0] / DFEAT;        // 50000
    const int E = in_sizes[4] / 2;            // 800000
    const int NC = in_sizes[15];              // 40

    const float* x1a = (const float*)d_in[0];
    const float* x1b = (const float*)d_in[1];
    const float* x2a = (const float*)d_in[2];
    const float* x2b = (const float*)d_in[3];
    const int* ei1 = (const int*)d_in[4];
    const int* ei2 = (const int*)d_in[5];
    const float* Wi = (const float*)d_in[6];
    const float* bi = (const float*)d_in[7];
    const float* gi = (const float*)d_in[8];
    const float* bei = (const float*)d_in[9];
    const float* Wm = (const float*)d_in[10];
    const float* bm = (const float*)d_in[11];
    const float* gm = (const float*)d_in[12];
    const float* bem = (const float*)d_in[13];
    const float* Wf = (const float*)d_in[14];
    const float* bf = (const float*)d_in[15];
    const float* fc1w1_W = (const float*)d_in[16];
    const float* fc1w1_b = (const float*)d_in[17];
    const float* fc1w2_W = (const float*)d_in[18];
    const float* fc1w2_b = (const float*)d_in[19];
    const float* aws_w1_W = (const float*)d_in[20];
    const float* aws_w1_b = (const float*)d_in[21];
    const float* aws_w2_W = (const float*)d_in[22];
    const float* aws_w2_b = (const float*)d_in[23];
    const float* fcw1_W = (const float*)d_in[24];
    const float* fcw1_b = (const float*)d_in[25];
    const float* fcw2_W = (const float*)d_in[26];
    const float* fcw2_b = (const float*)d_in[27];

    char* ws = (char*)d_ws;
    size_t off = 0;
    auto alloc = [&](size_t bytes) -> char* {
        char* p = ws + off;
        off += (bytes + 255) & ~(size_t)255;
        return p;
    };
    unsigned short* A = (unsigned short*)alloc((size_t)N * DFEAT * 2);
    unsigned short* B = (unsigned short*)alloc((size_t)N * DFEAT * 2);
    unsigned short* H1 = (unsigned short*)alloc((size_t)N * DFEAT * 2);
    unsigned short* H2 = (unsigned short*)alloc((size_t)N * DFEAT * 2);
    int* rp1 = (int*)alloc((size_t)(N + 1) * 4);
    int* rp2 = (int*)alloc((size_t)(N + 1) * 4);
    int* zb = (int*)alloc((size_t)4 * N * 4);  // cnt1|cnt2|fl1|fl2 — one memset
    int* cnt1 = zb;
    int* cnt2 = zb + N;
    int* fl1 = zb + 2 * N;
    int* fl2 = zb + 3 * N;
    float* dv1 = (float*)alloc((size_t)N * 4);
    float* dv2 = (float*)alloc((size_t)N * 4);
    int* cs1 = (int*)alloc((size_t)E * 4);
    int* cs2 = (int*)alloc((size_t)E * 4);
    unsigned short* Wt = (unsigned short*)alloc((size_t)2 * 16384 * 2);
    float* stats = (float*)alloc(2048);
    float* statsA = stats;
    float* statsB = stats + 256;
    float* ssbuf = (float*)alloc(2048);
    float* wout = (float*)alloc(256);
    int nb = (N + 2047) / 2048;  // 25
    int* bsums = (int*)alloc((size_t)2 * nb * 4);

    const int* src1 = ei1;
    const int* dst1 = ei1 + E;
    const int* src2 = ei2;
    const int* dst2 = ei2 + E;

    int rsz = (N + RANGES - 1) / RANGES;      // 6250 (<= MAXRSZ)
    int gemmbl = (N + 63) / 64;
    dim3 rgrid(RANGES * SLICES, 2);
    dim3 agggrid((N + 3) / 4, 2);
    dim3 statgrid((N + 127) / 128, 2);
    dim3 scangrid(nb, 2);
    dim3 l1grid(gemmbl, 4);
    dim3 prepgrid(64, 2);

    // ---- CSR build (range-partitioned) + weight prep ----
    hipMemsetAsync(zb, 0, (size_t)4 * N * 4, stream);
    prepW_kernel<<<prepgrid, 256, 0, stream>>>(Wm, Wt);
    countR_kernel<<<rgrid, 256, 0, stream>>>(dst1, dst2, cnt1, cnt2, N, E, rsz);
    blocksum_kernel<<<scangrid, 256, 0, stream>>>(cnt1, cnt2, bsums, N, nb);
    scansums_kernel<<<1, 64, 0, stream>>>(bsums, nb, rp1, rp2, N, E, stats);
    writerp_kernel<<<scangrid, 256, 0, stream>>>(cnt1, cnt2, bsums, rp1, rp2, dv1, dv2, N, nb);
    fillR_kernel<<<rgrid, 256, 0, stream>>>(src1, dst1, src2, dst2, rp1, rp2, fl1, fl2,
                                            cs1, cs2, N, E, rsz);

    // ---- Layer 1 ----
    gemm_l1_kernel<<<l1grid, 256, 0, stream>>>(x1a, x1b, x2a, x2b, Wi, H1, H2, N);
    dualagg_kernel<32, unsigned short><<<agggrid, 256, 0, stream>>>(
        H1, H2, rp1, cs1, dv1, rp2, cs2, dv2, bi, A, B, N);
    stats2_kernel<<<statgrid, 256, 0, stream>>>(A, B, stats, N);
    gate_prep_kernel<<<1, 128, 0, stream>>>(statsA, statsB, A, B, gi, bei, fc1w1_W, fc1w1_b,
                                            fc1w2_W, fc1w2_b, ssbuf, wout, N);

    // ---- Middle layer 0 (MFMA fused GEMM) ----
    gemm_mfma_kernel<<<gemmbl, 256, 0, stream>>>(A, B, ssbuf, wout, Wt, H1, N);
    dualagg_kernel<32, unsigned short><<<agggrid, 256, 0, stream>>>(
        H1, H1, rp1, cs1, dv1, rp2, cs2, dv2, bm, A, B, N);
    stats2_kernel<<<statgrid, 256, 0, stream>>>(A, B, stats, N);
    gate_prep_kernel<<<1, 128, 0, stream>>>(statsA, statsB, A, B, gm, bem, aws_w1_W, aws_w1_b,
                                            aws_w2_W, aws_w2_b, ssbuf, wout, N);

    // ---- Middle layer 1 ----
    gemm_mfma_kernel<<<gemmbl, 256, 0, stream>>>(A, B, ssbuf, wout, Wt + 16384, H1, N);
    dualagg_kernel<32, unsigned short><<<agggrid, 256, 0, stream>>>(
        H1, H1, rp1, cs1, dv1, rp2, cs2, dv2, bm + 128, A, B, N);
    stats2_kernel<<<statgrid, 256, 0, stream>>>(A, B, stats, N);
    gate_prep_kernel<<<1, 128, 0, stream>>>(statsA, statsB, A, B, gm + 128, bem + 128,
                                            aws_w1_W + 128, aws_w1_b + 1, aws_w2_W + 128,
                                            aws_w2_b + 1, ssbuf, wout, N);

    // ---- Final layer ----
    float* out0 = (float*)d_out;
    float* p1 = out0 + (size_t)N * NC;
    float* p2 = out0 + (size_t)2 * N * NC;
    gemm_fused_kernel<16, 4><<<gemmbl, 256, 0, stream>>>(A, B, ssbuf, wout, Wf, H2, N, NC, NC);
    dualagg_kernel<10, float><<<agggrid, 256, 0, stream>>>(H2, H2, rp1, cs1, dv1, rp2, cs2, dv2,
                                                           bf, p1, p2, N);
    gate_final_kernel<<<1, 64, 0, stream>>>(p1, p2, fcw1_W, fcw1_b, fcw2_W, fcw2_b, wout, N, NC);
    mix_kernel<<<(N * NC / 4 + 255) / 256, 256, 0, stream>>>(p1, p2, wout, out0, N * NC / 4);
}

// Round 3
// 763.301 us; speedup vs baseline: 1.1634x; 1.0301x over previous
//
#include <hip/hip_runtime.h>
#include <hip/hip_fp16.h>

// CLAGCN forward on MI355X.
// R1: stats 2-level. R2: multi-block scan. R3: bf16 staging + dual agg +
// fused combine. R4: revert stats to atomicAdd. R5: wave/node agg, bf16 A/B,
// fewer dispatches. R6: fill payload 4B; middle GEMMs -> MFMA bf16.
// R7 (FAILED): LDS-buffered bucket sort — fixed write amplification (112->9MB)
//     but barrier/flush latency chain at 15% occupancy made binA 158us.
// R8: dst-range-partitioned count+fill (8 ranges x 128 slices). fill WRITE
//     112->75MB, net 786us — but 75MB proves XCD pinning FAILED: 2-D grid
//     (x,y) linearization broke wgid%8==range.
// R9: (a) 1-D grid for countR/fillR, graph+slice folded into wgid>>3 so
//     wgid&7==range holds for every block -> each range's ~400KB cs window
//     resident in ONE XCD L2 -> dense write-back (pred WRITE ~10MB).
//     (b) cs payload = {fp16 norm, src:16}: fillR precomputes dv[s]*dv[d];
//     dualagg drops the dependent random dv[src] gather per edge.

#define DFEAT 128

typedef __attribute__((ext_vector_type(8))) short bf16x8;
typedef __attribute__((ext_vector_type(4))) float f32x4;

__device__ __forceinline__ unsigned short f2bf(float f) {
    unsigned u = __float_as_uint(f);
    u += 0x7fffu + ((u >> 16) & 1u);
    return (unsigned short)(u >> 16);
}
__device__ __forceinline__ float bf2f(unsigned short u) {
    return __uint_as_float((unsigned)u << 16);
}
__device__ __forceinline__ float4 bf4tof4(ushort4 u) {
    return make_float4(__uint_as_float((unsigned)u.x << 16),
                       __uint_as_float((unsigned)u.y << 16),
                       __uint_as_float((unsigned)u.z << 16),
                       __uint_as_float((unsigned)u.w << 16));
}
__device__ __forceinline__ unsigned f2h16(float f) {
    return (unsigned)__half_as_ushort(__float2half(f));
}
__device__ __forceinline__ float h16f(unsigned u) {
    return __half2float(__ushort_as_half((unsigned short)u));
}

// ---------------- ranged CSR build ----------------
constexpr int RANGES = 8;     // = XCD count; wgid & 7 -> XCD (round-robin)
constexpr int SLICES = 128;   // edge-stream slices per range
constexpr int MAXRSZ = 6400;  // >= ceil(N/RANGES); N=50000 -> 6250

// wgid = range + 8*(slice + SLICES*graph)  -> range == wgid%8 for ALL blocks
__global__ __launch_bounds__(256) void countR_kernel(
    const int* __restrict__ dst1, const int* __restrict__ dst2,
    int* __restrict__ cnt1, int* __restrict__ cnt2, int n, int E, int rsz) {
    int range = blockIdx.x & (RANGES - 1);
    int q = blockIdx.x >> 3;
    int slice = q & (SLICES - 1);
    int graph = q >> 7;   // SLICES == 128
    const int* dst = graph ? dst2 : dst1;
    int* cnt = graph ? cnt2 : cnt1;
    int r0 = range * rsz;
    int rn = min(rsz, n - r0);
    if (rn <= 0) return;
    __shared__ int hist[MAXRSZ];
    int t = threadIdx.x;
    for (int i = t; i < rn; i += 256) hist[i] = 0;
    __syncthreads();
    int es = (E + SLICES - 1) / SLICES;
    int e0 = slice * es;
    int e1 = min(e0 + es, E);
    for (int i = e0 + t; i < e1; i += 256) {
        unsigned d = (unsigned)(dst[i] - r0);
        if (d < (unsigned)rn) atomicAdd(&hist[d], 1);
    }
    __syncthreads();
    for (int i = t; i < rn; i += 256) {
        int v = hist[i];
        if (v) atomicAdd(&cnt[r0 + i], v);
    }
}

__global__ __launch_bounds__(256) void fillR_kernel(
    const int* __restrict__ src1, const int* __restrict__ dst1,
    const int* __restrict__ src2, const int* __restrict__ dst2,
    const int* __restrict__ rp1, const int* __restrict__ rp2,
    const float* __restrict__ dv1, const float* __restrict__ dv2,
    int* __restrict__ fl1, int* __restrict__ fl2,
    int* __restrict__ cs1, int* __restrict__ cs2, int n, int E, int rsz) {
    int range = blockIdx.x & (RANGES - 1);
    int q = blockIdx.x >> 3;
    int slice = q & (SLICES - 1);
    int graph = q >> 7;
    const int *src, *dst, *rp;
    const float* dv;
    int *fl, *cs;
    if (graph == 0) { src = src1; dst = dst1; rp = rp1; dv = dv1; fl = fl1; cs = cs1; }
    else            { src = src2; dst = dst2; rp = rp2; dv = dv2; fl = fl2; cs = cs2; }
    int r0 = range * rsz;
    int rn = min(rsz, n - r0);
    if (rn <= 0) return;
    int es = (E + SLICES - 1) / SLICES;
    int e0 = slice * es;
    int e1 = min(e0 + es, E);
    for (int i = e0 + (int)threadIdx.x; i < e1; i += 256) {
        int d = dst[i];
        if ((unsigned)(d - r0) < (unsigned)rn) {
            int s = src[i];
            float w = dv[d] * dv[s];
            int pos = rp[d] + atomicAdd(&fl[d], 1);
            cs[pos] = (int)((f2h16(w) << 16) | (unsigned)s);  // {fp16 norm, src:16}
        }
    }
}

// ---------------- CSR scan (unchanged) ----------------
__global__ __launch_bounds__(256) void blocksum_kernel(const int* __restrict__ c1,
                                                       const int* __restrict__ c2,
                                                       int* __restrict__ bs, int n, int nb) {
    const int* c = blockIdx.y ? c2 : c1;
    int* out = bs + (size_t)blockIdx.y * nb;
    int t = threadIdx.x;
    int base = blockIdx.x * 2048 + t * 8;
    int s = 0;
#pragma unroll
    for (int i = 0; i < 8; ++i) {
        int idx = base + i;
        if (idx < n) s += c[idx];
    }
    __shared__ int red[256];
    red[t] = s;
    __syncthreads();
    for (int o = 128; o > 0; o >>= 1) {
        if (t < o) red[t] += red[t + o];
        __syncthreads();
    }
    if (t == 0) out[blockIdx.x] = red[0];
}

__global__ void scansums_kernel(int* __restrict__ bs, int nb, int* __restrict__ rp1,
                                int* __restrict__ rp2, int n, int E, float* __restrict__ stats) {
    int t = threadIdx.x;  // 64 threads
    if (t < 2) {
        int* b = bs + (size_t)t * nb;
        int run = 0;
        for (int i = 0; i < nb; ++i) {
            int v = b[i];
            b[i] = run;
            run += v;
        }
        (t ? rp2 : rp1)[n] = E;
    }
    for (int i = t; i < 512; i += 64) stats[i] = 0.f;
}

__global__ __launch_bounds__(256) void writerp_kernel(const int* __restrict__ c1,
                                                      const int* __restrict__ c2,
                                                      const int* __restrict__ bs,
                                                      int* __restrict__ rp1, int* __restrict__ rp2,
                                                      float* __restrict__ dv1,
                                                      float* __restrict__ dv2, int n, int nb) {
    const int* c = blockIdx.y ? c2 : c1;
    int* rp = blockIdx.y ? rp2 : rp1;
    float* dv = blockIdx.y ? dv2 : dv1;
    int boff = bs[(size_t)blockIdx.y * nb + blockIdx.x];
    int t = threadIdx.x;
    int base = blockIdx.x * 2048 + t * 8;
    int v[8];
    int s = 0;
#pragma unroll
    for (int i = 0; i < 8; ++i) {
        int idx = base + i;
        v[i] = (idx < n) ? c[idx] : 0;
        s += v[i];
    }
    __shared__ int red[256];
    red[t] = s;
    __syncthreads();
    for (int o = 1; o < 256; o <<= 1) {
        int x = (t >= o) ? red[t - o] : 0;
        __syncthreads();
        red[t] += x;
        __syncthreads();
    }
    int run = boff + red[t] - s;
#pragma unroll
    for (int i = 0; i < 8; ++i) {
        int idx = base + i;
        if (idx < n) {
            rp[idx] = run;
            dv[idx] = rsqrtf((float)(v[i] + 1));  // +1 self-loop
            run += v[i];
        }
    }
}

// ---------------- dual aggregation: one wave per node ----------------
// cs payload packed {fp16 norm, src:16}; no dv gather on the edge path.
template <int FV, typename OutT>
__global__ __launch_bounds__(256) void dualagg_kernel(
    const unsigned short* __restrict__ h1, const unsigned short* __restrict__ h2,
    const int* __restrict__ rp1, const int* __restrict__ cs1, const float* __restrict__ dv1,
    const int* __restrict__ rp2, const int* __restrict__ cs2, const float* __restrict__ dv2,
    const float* __restrict__ bias, OutT* __restrict__ o1, OutT* __restrict__ o2, int n) {
    constexpr int COLS = FV * 4;
    const unsigned short* h;
    const int *rp, *cs;
    const float* dv;
    OutT* out;
    if (blockIdx.y == 0) { h = h1; rp = rp1; cs = cs1; dv = dv1; out = o1; }
    else                 { h = h2; rp = rp2; cs = cs2; dv = dv2; out = o2; }
    int wid = blockIdx.x * 4 + (threadIdx.x >> 6);
    if (wid >= n) return;
    int lane = threadIdx.x & 63;
    int half = lane >> 5;
    int l = lane & 31;
    bool act = (l < FV);
    float4 acc = make_float4(0.f, 0.f, 0.f, 0.f);
    int e0 = rp[wid], e1 = rp[wid + 1];
    int e = e0 + half;
    for (; e + 6 < e1; e += 8) {
        int va = cs[e], vb = cs[e + 2], vc = cs[e + 4], vd = cs[e + 6];
        float wa = h16f((unsigned)va >> 16); int sa = va & 0xFFFF;
        float wb = h16f((unsigned)vb >> 16); int sb = vb & 0xFFFF;
        float wc = h16f((unsigned)vc >> 16); int sc = vc & 0xFFFF;
        float wd = h16f((unsigned)vd >> 16); int sd = vd & 0xFFFF;
        if (act) {
            float4 ha = bf4tof4(((const ushort4*)(h + (size_t)sa * COLS))[l]);
            float4 hb = bf4tof4(((const ushort4*)(h + (size_t)sb * COLS))[l]);
            float4 hc = bf4tof4(((const ushort4*)(h + (size_t)sc * COLS))[l]);
            float4 hd = bf4tof4(((const ushort4*)(h + (size_t)sd * COLS))[l]);
            acc.x = fmaf(wa, ha.x, acc.x); acc.y = fmaf(wa, ha.y, acc.y);
            acc.z = fmaf(wa, ha.z, acc.z); acc.w = fmaf(wa, ha.w, acc.w);
            acc.x = fmaf(wb, hb.x, acc.x); acc.y = fmaf(wb, hb.y, acc.y);
            acc.z = fmaf(wb, hb.z, acc.z); acc.w = fmaf(wb, hb.w, acc.w);
            acc.x = fmaf(wc, hc.x, acc.x); acc.y = fmaf(wc, hc.y, acc.y);
            acc.z = fmaf(wc, hc.z, acc.z); acc.w = fmaf(wc, hc.w, acc.w);
            acc.x = fmaf(wd, hd.x, acc.x); acc.y = fmaf(wd, hd.y, acc.y);
            acc.z = fmaf(wd, hd.z, acc.z); acc.w = fmaf(wd, hd.w, acc.w);
        }
    }
    for (; e < e1; e += 2) {
        int va = cs[e];
        float wa = h16f((unsigned)va >> 16); int sa = va & 0xFFFF;
        if (act) {
            float4 ha = bf4tof4(((const ushort4*)(h + (size_t)sa * COLS))[l]);
            acc.x = fmaf(wa, ha.x, acc.x); acc.y = fmaf(wa, ha.y, acc.y);
            acc.z = fmaf(wa, ha.z, acc.z); acc.w = fmaf(wa, ha.w, acc.w);
        }
    }
    acc.x += __shfl_xor(acc.x, 32);
    acc.y += __shfl_xor(acc.y, 32);
    acc.z += __shfl_xor(acc.z, 32);
    acc.w += __shfl_xor(acc.w, 32);
    if (half == 0 && act) {
        float dn = dv[wid];
        float w = dn * dn;  // self-loop norm
        float4 hv = bf4tof4(((const ushort4*)(h + (size_t)wid * COLS))[l]);
        acc.x = fmaf(w, hv.x, acc.x); acc.y = fmaf(w, hv.y, acc.y);
        acc.z = fmaf(w, hv.z, acc.z); acc.w = fmaf(w, hv.w, acc.w);
        float4 b = ((const float4*)bias)[l];
        acc.x += b.x; acc.y += b.y; acc.z += b.z; acc.w += b.w;
        if constexpr (sizeof(OutT) == 4) {
            ((float4*)((float*)out + (size_t)wid * COLS))[l] = acc;
        } else {
            ushort4 o;
            o.x = f2bf(acc.x); o.y = f2bf(acc.y); o.z = f2bf(acc.z); o.w = f2bf(acc.w);
            ((ushort4*)((unsigned short*)out + (size_t)wid * COLS))[l] = o;
        }
    }
}

// ---------------- Layer-1 quad GEMM ----------------
__global__ __launch_bounds__(256) void gemm_l1_kernel(
    const float* __restrict__ x1a, const float* __restrict__ x1b, const float* __restrict__ x2a,
    const float* __restrict__ x2b, const float* __restrict__ Wi, unsigned short* __restrict__ H1,
    unsigned short* __restrict__ H2, int nrows) {
    constexpr int CG = 16;
    const float* X = (blockIdx.y == 0) ? x1a : (blockIdx.y == 1) ? x1b
                     : (blockIdx.y == 2) ? x2a : x2b;
    const float* W = Wi + (blockIdx.y & 1) * 128 * 64;
    unsigned short* Y = (blockIdx.y < 2) ? H1 : H2;
    int ocol = (int)(blockIdx.y & 1) * 64;
    __shared__ float Ws[32][64];
    __shared__ float Xs[64][32];
    int tid = threadIdx.x;
    int row0 = blockIdx.x * 64;
    int cg = tid % CG;
    int rg = tid / CG;
    float4 acc[4];
#pragma unroll
    for (int i = 0; i < 4; ++i) acc[i] = make_float4(0.f, 0.f, 0.f, 0.f);
    for (int kc = 0; kc < 4; ++kc) {
        for (int i = tid; i < 32 * CG; i += 256) {
            int r = i / CG, c = i % CG;
            *(float4*)&Ws[r][c * 4] = *(const float4*)(W + (size_t)(kc * 32 + r) * 64 + c * 4);
        }
        for (int i = tid; i < 64 * 8; i += 256) {
            int r = i / 8, c = i % 8;
            int gr = row0 + r;
            float4 v = make_float4(0.f, 0.f, 0.f, 0.f);
            if (gr < nrows) v = *(const float4*)(X + (size_t)gr * DFEAT + kc * 32 + c * 4);
            *(float4*)&Xs[r][c * 4] = v;
        }
        __syncthreads();
#pragma unroll
        for (int k = 0; k < 32; ++k) {
            float4 w = *(float4*)&Ws[k][cg * 4];
#pragma unroll
            for (int i = 0; i < 4; ++i) {
                float a = Xs[rg * 4 + i][k];
                acc[i].x = fmaf(a, w.x, acc[i].x);
                acc[i].y = fmaf(a, w.y, acc[i].y);
                acc[i].z = fmaf(a, w.z, acc[i].z);
                acc[i].w = fmaf(a, w.w, acc[i].w);
            }
        }
        __syncthreads();
    }
#pragma unroll
    for (int i = 0; i < 4; ++i) {
        int r = row0 + rg * 4 + i;
        if (r < nrows) {
            ushort4 o;
            o.x = f2bf(acc[i].x); o.y = f2bf(acc[i].y);
            o.z = f2bf(acc[i].z); o.w = f2bf(acc[i].w);
            *(ushort4*)(Y + (size_t)r * DFEAT + ocol + cg * 4) = o;
        }
    }
}

// ---------------- prepW: Wm (2x128x128 fp32) -> bf16 transposed [l][kc][col][kk] ----------------
__global__ __launch_bounds__(256) void prepW_kernel(const float* __restrict__ Wm,
                                                    unsigned short* __restrict__ Wt) {
    int o = blockIdx.x * 256 + threadIdx.x;  // 16384 per layer
    int l = blockIdx.y;
    int kk = o & 31;
    int col = (o >> 5) & 127;
    int kc = o >> 12;
    int k = kc * 32 + kk;
    Wt[(size_t)l * 16384 + o] = f2bf(Wm[(size_t)l * 16384 + (size_t)k * 128 + col]);
}

// ---------------- MFMA fused GEMM (128->128): x = w1*relu(bn(A)) + w2*relu(bn(B)) ----------------
__global__ __launch_bounds__(256) void gemm_mfma_kernel(
    const unsigned short* __restrict__ Abf, const unsigned short* __restrict__ Bbf,
    const float* __restrict__ ss, const float* __restrict__ wout,
    const unsigned short* __restrict__ Wt, unsigned short* __restrict__ Y, int nrows) {
    __shared__ short Xs[64][128];
    int tid = threadIdx.x;
    int row0 = blockIdx.x * 64;
    int wave = tid >> 6, lane = tid & 63;
    int m = lane & 15, quad = lane >> 4;
    float w1 = wout[0], w2 = wout[1];
    for (int u = tid; u < 1024; u += 256) {
        int r = u >> 4;
        int col0 = (u & 15) * 8;
        int gr = row0 + r;
        if (gr < nrows) {
#pragma unroll
            for (int hh = 0; hh < 2; ++hh) {
                int c = col0 + hh * 4;
                float4 fa = bf4tof4(*(const ushort4*)(Abf + (size_t)gr * 128 + c));
                float4 fb = bf4tof4(*(const ushort4*)(Bbf + (size_t)gr * 128 + c));
                float4 sa = *(const float4*)(ss + c);
                float4 ha = *(const float4*)(ss + 128 + c);
                float4 sb = *(const float4*)(ss + 256 + c);
                float4 hb = *(const float4*)(ss + 384 + c);
                ushort4 o;
                o.x = f2bf(w1 * fmaxf(fmaf(fa.x, sa.x, ha.x), 0.f) +
                           w2 * fmaxf(fmaf(fb.x, sb.x, hb.x), 0.f));
                o.y = f2bf(w1 * fmaxf(fmaf(fa.y, sa.y, ha.y), 0.f) +
                           w2 * fmaxf(fmaf(fb.y, sb.y, hb.y), 0.f));
                o.z = f2bf(w1 * fmaxf(fmaf(fa.z, sa.z, ha.z), 0.f) +
                           w2 * fmaxf(fmaf(fb.z, sb.z, hb.z), 0.f));
                o.w = f2bf(w1 * fmaxf(fmaf(fa.w, sa.w, ha.w), 0.f) +
                           w2 * fmaxf(fmaf(fb.w, sb.w, hb.w), 0.f));
                *(ushort4*)&Xs[r][c] = o;
            }
        } else {
            ushort4 z = {0, 0, 0, 0};
            *(ushort4*)&Xs[r][col0] = z;
            *(ushort4*)&Xs[r][col0 + 4] = z;
        }
    }
    __syncthreads();
    f32x4 acc[8];
#pragma unroll
    for (int i = 0; i < 8; ++i) acc[i] = (f32x4){0.f, 0.f, 0.f, 0.f};
#pragma unroll
    for (int kc = 0; kc < 4; ++kc) {
        bf16x8 a = *(const bf16x8*)&Xs[wave * 16 + m][kc * 32 + quad * 8];
#pragma unroll
        for (int ct = 0; ct < 8; ++ct) {
            const short* bp = (const short*)(Wt + ((size_t)(kc * 128 + ct * 16 + m) * 32) + quad * 8);
            bf16x8 b = *(const bf16x8*)bp;
            acc[ct] = __builtin_amdgcn_mfma_f32_16x16x32_bf16(a, b, acc[ct], 0, 0, 0);
        }
    }
#pragma unroll
    for (int ct = 0; ct < 8; ++ct) {
#pragma unroll
        for (int i = 0; i < 4; ++i) {
            int gr = row0 + wave * 16 + quad * 4 + i;
            if (gr < nrows) Y[(size_t)gr * 128 + ct * 16 + m] = f2bf(acc[ct][i]);
        }
    }
}

// ---------------- VALU fused GEMM (final 128->40) ----------------
template <int CG, int RPT>
__global__ __launch_bounds__(256) void gemm_fused_kernel(
    const unsigned short* __restrict__ Abf, const unsigned short* __restrict__ Bbf,
    const float* __restrict__ ss, const float* __restrict__ wout, const float* __restrict__ W,
    unsigned short* __restrict__ Y, int nrows, int fout, int ostride) {
    __shared__ float Ws[32][CG * 4];
    __shared__ float Xs[64][32];
    int tid = threadIdx.x;
    int row0 = blockIdx.x * 64;
    int cg = tid % CG;
    int rg = tid / CG;
    float w1 = wout[0], w2 = wout[1];
    float4 acc[RPT];
#pragma unroll
    for (int i = 0; i < RPT; ++i) acc[i] = make_float4(0.f, 0.f, 0.f, 0.f);
    for (int kc = 0; kc < 4; ++kc) {
        for (int i = tid; i < 32 * CG; i += 256) {
            int r = i / CG, c = i % CG;
            float4 w;
            if ((c * 4 + 3) < fout) {
                w = *(const float4*)(W + (size_t)(kc * 32 + r) * fout + c * 4);
            } else {
                float t0 = (c * 4 + 0) < fout ? W[(size_t)(kc * 32 + r) * fout + c * 4 + 0] : 0.f;
                float t1 = (c * 4 + 1) < fout ? W[(size_t)(kc * 32 + r) * fout + c * 4 + 1] : 0.f;
                float t2 = (c * 4 + 2) < fout ? W[(size_t)(kc * 32 + r) * fout + c * 4 + 2] : 0.f;
                float t3 = (c * 4 + 3) < fout ? W[(size_t)(kc * 32 + r) * fout + c * 4 + 3] : 0.f;
                w = make_float4(t0, t1, t2, t3);
            }
            *(float4*)&Ws[r][c * 4] = w;
        }
        for (int i = tid; i < 64 * 8; i += 256) {
            int r = i / 8, c = i % 8;
            int gr = row0 + r;
            int col0 = kc * 32 + c * 4;
            float4 v = make_float4(0.f, 0.f, 0.f, 0.f);
            if (gr < nrows) {
                float4 a = bf4tof4(*(const ushort4*)(Abf + (size_t)gr * DFEAT + col0));
                float4 b = bf4tof4(*(const ushort4*)(Bbf + (size_t)gr * DFEAT + col0));
                float4 scA = *(const float4*)(ss + col0);
                float4 shA = *(const float4*)(ss + DFEAT + col0);
                float4 scB = *(const float4*)(ss + 2 * DFEAT + col0);
                float4 shB = *(const float4*)(ss + 3 * DFEAT + col0);
                v.x = w1 * fmaxf(fmaf(a.x, scA.x, shA.x), 0.f) +
                      w2 * fmaxf(fmaf(b.x, scB.x, shB.x), 0.f);
                v.y = w1 * fmaxf(fmaf(a.y, scA.y, shA.y), 0.f) +
                      w2 * fmaxf(fmaf(b.y, scB.y, shB.y), 0.f);
                v.z = w1 * fmaxf(fmaf(a.z, scA.z, shA.z), 0.f) +
                      w2 * fmaxf(fmaf(b.z, scB.z, shB.z), 0.f);
                v.w = w1 * fmaxf(fmaf(a.w, scA.w, shA.w), 0.f) +
                      w2 * fmaxf(fmaf(b.w, scB.w, shB.w), 0.f);
            }
            *(float4*)&Xs[r][c * 4] = v;
        }
        __syncthreads();
#pragma unroll
        for (int k = 0; k < 32; ++k) {
            float4 w = *(float4*)&Ws[k][cg * 4];
#pragma unroll
            for (int i = 0; i < RPT; ++i) {
                float a = Xs[rg * RPT + i][k];
                acc[i].x = fmaf(a, w.x, acc[i].x);
                acc[i].y = fmaf(a, w.y, acc[i].y);
                acc[i].z = fmaf(a, w.z, acc[i].z);
                acc[i].w = fmaf(a, w.w, acc[i].w);
            }
        }
        __syncthreads();
    }
    if (cg * 4 < fout) {
#pragma unroll
        for (int i = 0; i < RPT; ++i) {
            int r = row0 + rg * RPT + i;
            if (r < nrows) {
                ushort4 o;
                o.x = f2bf(acc[i].x); o.y = f2bf(acc[i].y);
                o.z = f2bf(acc[i].z); o.w = f2bf(acc[i].w);
                *(ushort4*)(Y + (size_t)r * ostride + cg * 4) = o;
            }
        }
    }
}

// ---------------- BN statistics: 2-level atomicAdd ----------------
__global__ __launch_bounds__(256) void stats2_kernel(const unsigned short* __restrict__ A,
                                                     const unsigned short* __restrict__ B,
                                                     float* __restrict__ stats, int nrows) {
    __shared__ float red1[256];
    __shared__ float red2[256];
    int t = threadIdx.x;
    int col = t & 127;
    int rg = t >> 7;
    const unsigned short* src = (blockIdx.y == 0) ? A : B;
    float* st = stats + (size_t)blockIdx.y * 256;
    int r0 = blockIdx.x * 128 + rg * 64;
    int r1 = min(r0 + 64, nrows);
    float s = 0.f, s2 = 0.f;
    for (int r = r0; r < r1; ++r) {
        float v = bf2f(src[(size_t)r * DFEAT + col]);
        s += v;
        s2 = fmaf(v, v, s2);
    }
    red1[t] = s;
    red2[t] = s2;
    __syncthreads();
    if (t < 128) {
        atomicAdd(&st[col], red1[t] + red1[t + 128]);
        atomicAdd(&st[DFEAT + col], red2[t] + red2[t + 128]);
    }
}

// ---------------- BN scale/shift + gates; zeros stats for next layer ----------------
__global__ __launch_bounds__(128) void gate_prep_kernel(
    float* __restrict__ statsA, float* __restrict__ statsB,
    const unsigned short* __restrict__ preA, const unsigned short* __restrict__ preB,
    const float* __restrict__ gamma, const float* __restrict__ beta,
    const float* __restrict__ gwA, const float* __restrict__ gbA,
    const float* __restrict__ gwB, const float* __restrict__ gbB,
    float* __restrict__ ss, float* __restrict__ wout, int nrows) {
    __shared__ float red[128];
    __shared__ float dotA_s;
    int t = threadIdx.x;
    float invN = 1.f / (float)nrows;
    float meanA = statsA[t] * invN;
    float varA = statsA[DFEAT + t] * invN - meanA * meanA;
    float scA = gamma[t] * rsqrtf(varA + 1e-5f);
    float shA = beta[t] - meanA * scA;
    ss[t] = scA;
    ss[DFEAT + t] = shA;
    float meanB = statsB[t] * invN;
    float varB = statsB[DFEAT + t] * invN - meanB * meanB;
    float scB = gamma[t] * rsqrtf(varB + 1e-5f);
    float shB = beta[t] - meanB * scB;
    ss[2 * DFEAT + t] = scB;
    ss[3 * DFEAT + t] = shB;
    statsA[t] = 0.f;
    statsA[DFEAT + t] = 0.f;
    statsB[t] = 0.f;
    statsB[DFEAT + t] = 0.f;
    float av = fmaxf(fmaf(bf2f(preA[(size_t)(nrows - 1) * DFEAT + t]), scA, shA), 0.f);
    red[t] = av * gwA[t];
    __syncthreads();
    for (int s = 64; s > 0; s >>= 1) {
        if (t < s) red[t] += red[t + s];
        __syncthreads();
    }
    if (t == 0) dotA_s = red[0];
    __syncthreads();
    float bv = fmaxf(fmaf(bf2f(preB[(size_t)(nrows - 1) * DFEAT + t]), scB, shB), 0.f);
    red[t] = bv * gwB[t];
    __syncthreads();
    for (int s = 64; s > 0; s >>= 1) {
        if (t < s) red[t] += red[t + s];
        __syncthreads();
    }
    if (t == 0) {
        float s1 = 1.f / (1.f + expf(-(dotA_s + gbA[0])));
        float s2 = 1.f / (1.f + expf(-(red[0] + gbB[0])));
        float tt = s1 + s2;
        wout[0] = s1 / tt;
        wout[1] = s2 / tt;
    }
}

__global__ __launch_bounds__(64) void gate_final_kernel(
    const float* __restrict__ p1, const float* __restrict__ p2,
    const float* __restrict__ w1v, const float* __restrict__ b1,
    const float* __restrict__ w2v, const float* __restrict__ b2,
    float* __restrict__ wout, int nrows, int nclass) {
    __shared__ float red[64];
    __shared__ float dot1_s;
    int t = threadIdx.x;
    float v = (t < nclass) ? p1[(size_t)(nrows - 1) * nclass + t] * w1v[t] : 0.f;
    red[t] = v;
    __syncthreads();
    for (int s = 32; s > 0; s >>= 1) {
        if (t < s) red[t] += red[t + s];
        __syncthreads();
    }
    if (t == 0) dot1_s = red[0];
    __syncthreads();
    v = (t < nclass) ? p2[(size_t)(nrows - 1) * nclass + t] * w2v[t] : 0.f;
    red[t] = v;
    __syncthreads();
    for (int s = 32; s > 0; s >>= 1) {
        if (t < s) red[t] += red[t + s];
        __syncthreads();
    }
    if (t == 0) {
        float s1 = 1.f / (1.f + expf(-(dot1_s + b1[0])));
        float s2 = 1.f / (1.f + expf(-(red[0] + b2[0])));
        float tt = s1 + s2;
        wout[0] = s1 / tt;
        wout[1] = s2 / tt;
    }
}

__global__ __launch_bounds__(256) void mix_kernel(const float* __restrict__ p1,
                                                  const float* __restrict__ p2,
                                                  const float* __restrict__ wout,
                                                  float* __restrict__ o, int n4) {
    int idx = blockIdx.x * blockDim.x + threadIdx.x;
    if (idx >= n4) return;
    float w1 = wout[0], w2 = wout[1];
    float4 a = *(const float4*)(p1 + (size_t)idx * 4);
    float4 b = *(const float4*)(p2 + (size_t)idx * 4);
    float4 r = make_float4(w1 * a.x + w2 * b.x, w1 * a.y + w2 * b.y, w1 * a.z + w2 * b.z,
                           w1 * a.w + w2 * b.w);
    *(float4*)(o + (size_t)idx * 4) = r;
}

extern "C" void kernel_launch(void* const* d_in, const int* in_sizes, int n_in, void* d_out,
                              int out_size, void* d_ws, size_t ws_size, hipStream_t stream) {
    (void)n_in; (void)out_size; (void)ws_size;
    const int N = in_sizes[0] / DFEAT;        // 50000
    const int E = in_sizes[4] / 2;            // 800000
    const int NC = in_sizes[15];              // 40

    const float* x1a = (const float*)d_in[0];
    const float* x1b = (const float*)d_in[1];
    const float* x2a = (const float*)d_in[2];
    const float* x2b = (const float*)d_in[3];
    const int* ei1 = (const int*)d_in[4];
    const int* ei2 = (const int*)d_in[5];
    const float* Wi = (const float*)d_in[6];
    const float* bi = (const float*)d_in[7];
    const float* gi = (const float*)d_in[8];
    const float* bei = (const float*)d_in[9];
    const float* Wm = (const float*)d_in[10];
    const float* bm = (const float*)d_in[11];
    const float* gm = (const float*)d_in[12];
    const float* bem = (const float*)d_in[13];
    const float* Wf = (const float*)d_in[14];
    const float* bf = (const float*)d_in[15];
    const float* fc1w1_W = (const float*)d_in[16];
    const float* fc1w1_b = (const float*)d_in[17];
    const float* fc1w2_W = (const float*)d_in[18];
    const float* fc1w2_b = (const float*)d_in[19];
    const float* aws_w1_W = (const float*)d_in[20];
    const float* aws_w1_b = (const float*)d_in[21];
    const float* aws_w2_W = (const float*)d_in[22];
    const float* aws_w2_b = (const float*)d_in[23];
    const float* fcw1_W = (const float*)d_in[24];
    const float* fcw1_b = (const float*)d_in[25];
    const float* fcw2_W = (const float*)d_in[26];
    const float* fcw2_b = (const float*)d_in[27];

    char* ws = (char*)d_ws;
    size_t off = 0;
    auto alloc = [&](size_t bytes) -> char* {
        char* p = ws + off;
        off += (bytes + 255) & ~(size_t)255;
        return p;
    };
    unsigned short* A = (unsigned short*)alloc((size_t)N * DFEAT * 2);
    unsigned short* B = (unsigned short*)alloc((size_t)N * DFEAT * 2);
    unsigned short* H1 = (unsigned short*)alloc((size_t)N * DFEAT * 2);
    unsigned short* H2 = (unsigned short*)alloc((size_t)N * DFEAT * 2);
    int* rp1 = (int*)alloc((size_t)(N + 1) * 4);
    int* rp2 = (int*)alloc((size_t)(N + 1) * 4);
    int* zb = (int*)alloc((size_t)4 * N * 4);  // cnt1|cnt2|fl1|fl2 — one memset
    int* cnt1 = zb;
    int* cnt2 = zb + N;
    int* fl1 = zb + 2 * N;
    int* fl2 = zb + 3 * N;
    float* dv1 = (float*)alloc((size_t)N * 4);
    float* dv2 = (float*)alloc((size_t)N * 4);
    int* cs1 = (int*)alloc((size_t)E * 4);
    int* cs2 = (int*)alloc((size_t)E * 4);
    unsigned short* Wt = (unsigned short*)alloc((size_t)2 * 16384 * 2);
    float* stats = (float*)alloc(2048);
    float* statsA = stats;
    float* statsB = stats + 256;
    float* ssbuf = (float*)alloc(2048);
    float* wout = (float*)alloc(256);
    int nb = (N + 2047) / 2048;  // 25
    int* bsums = (int*)alloc((size_t)2 * nb * 4);

    const int* src1 = ei1;
    const int* dst1 = ei1 + E;
    const int* src2 = ei2;
    const int* dst2 = ei2 + E;

    int rsz = (N + RANGES - 1) / RANGES;      // 6250 (<= MAXRSZ)
    int gemmbl = (N + 63) / 64;
    dim3 rgrid1d(RANGES * SLICES * 2);        // 1-D: wgid&7 == range for ALL blocks
    dim3 agggrid((N + 3) / 4, 2);
    dim3 statgrid((N + 127) / 128, 2);
    dim3 scangrid(nb, 2);
    dim3 l1grid(gemmbl, 4);
    dim3 prepgrid(64, 2);

    // ---- CSR build (range-partitioned, XCD-pinned) + weight prep ----
    hipMemsetAsync(zb, 0, (size_t)4 * N * 4, stream);
    prepW_kernel<<<prepgrid, 256, 0, stream>>>(Wm, Wt);
    countR_kernel<<<rgrid1d, 256, 0, stream>>>(dst1, dst2, cnt1, cnt2, N, E, rsz);
    blocksum_kernel<<<scangrid, 256, 0, stream>>>(cnt1, cnt2, bsums, N, nb);
    scansums_kernel<<<1, 64, 0, stream>>>(bsums, nb, rp1, rp2, N, E, stats);
    writerp_kernel<<<scangrid, 256, 0, stream>>>(cnt1, cnt2, bsums, rp1, rp2, dv1, dv2, N, nb);
    fillR_kernel<<<rgrid1d, 256, 0, stream>>>(src1, dst1, src2, dst2, rp1, rp2, dv1, dv2,
                                              fl1, fl2, cs1, cs2, N, E, rsz);

    // ---- Layer 1 ----
    gemm_l1_kernel<<<l1grid, 256, 0, stream>>>(x1a, x1b, x2a, x2b, Wi, H1, H2, N);
    dualagg_kernel<32, unsigned short><<<agggrid, 256, 0, stream>>>(
        H1, H2, rp1, cs1, dv1, rp2, cs2, dv2, bi, A, B, N);
    stats2_kernel<<<statgrid, 256, 0, stream>>>(A, B, stats, N);
    gate_prep_kernel<<<1, 128, 0, stream>>>(statsA, statsB, A, B, gi, bei, fc1w1_W, fc1w1_b,
                                            fc1w2_W, fc1w2_b, ssbuf, wout, N);

    // ---- Middle layer 0 (MFMA fused GEMM) ----
    gemm_mfma_kernel<<<gemmbl, 256, 0, stream>>>(A, B, ssbuf, wout, Wt, H1, N);
    dualagg_kernel<32, unsigned short><<<agggrid, 256, 0, stream>>>(
        H1, H1, rp1, cs1, dv1, rp2, cs2, dv2, bm, A, B, N);
    stats2_kernel<<<statgrid, 256, 0, stream>>>(A, B, stats, N);
    gate_prep_kernel<<<1, 128, 0, stream>>>(statsA, statsB, A, B, gm, bem, aws_w1_W, aws_w1_b,
                                            aws_w2_W, aws_w2_b, ssbuf, wout, N);

    // ---- Middle layer 1 ----
    gemm_mfma_kernel<<<gemmbl, 256, 0, stream>>>(A, B, ssbuf, wout, Wt + 16384, H1, N);
    dualagg_kernel<32, unsigned short><<<agggrid, 256, 0, stream>>>(
        H1, H1, rp1, cs1, dv1, rp2, cs2, dv2, bm + 128, A, B, N);
    stats2_kernel<<<statgrid, 256, 0, stream>>>(A, B, stats, N);
    gate_prep_kernel<<<1, 128, 0, stream>>>(statsA, statsB, A, B, gm + 128, bem + 128,
                                            aws_w1_W + 128, aws_w1_b + 1, aws_w2_W + 128,
                                            aws_w2_b + 1, ssbuf, wout, N);

    // ---- Final layer ----
    float* out0 = (float*)d_out;
    float* p1 = out0 + (size_t)N * NC;
    float* p2 = out0 + (size_t)2 * N * NC;
    gemm_fused_kernel<16, 4><<<gemmbl, 256, 0, stream>>>(A, B, ssbuf, wout, Wf, H2, N, NC, NC);
    dualagg_kernel<10, float><<<agggrid, 256, 0, stream>>>(H2, H2, rp1, cs1, dv1, rp2, cs2, dv2,
                                                           bf, p1, p2, N);
    gate_final_kernel<<<1, 64, 0, stream>>>(p1, p2, fcw1_W, fcw1_b, fcw2_W, fcw2_b, wout, N, NC);
    mix_kernel<<<(N * NC / 4 + 255) / 256, 256, 0, stream>>>(p1, p2, wout, out0, N * NC / 4);
}

// Round 4
// 757.552 us; speedup vs baseline: 1.1722x; 1.0076x over previous
//
#include <hip/hip_runtime.h>
#include <hip/hip_fp16.h>

// CLAGCN forward on MI355X.
// R1-R6: see history. R7 (FAILED): LDS bucket sort, barrier-latency-bound.
// R8/R9: dst-range partition + fp16-norm payload; 763us. WRITE stayed 83MB
//     despite XCD pinning -> partial-line theory falsified. Culprit: 1.6M
//     device-scope atomicAdd(&fl[d]) — on gfx950 cross-XCD coherence forces
//     every global atomic to the memory-side coherence point (~50-100MB EA
//     write traffic + serialization). countR's global-atomic merge same.
// R10: CSR build with ZERO global atomics — deterministic counting sort:
//     histRS: per-(range,slice,graph) LDS hist -> DENSE write to
//             base[g][slice][node] (exclusive ownership, no atomics);
//     slicescan: per-node exclusive prefix over slices (coalesced) -> cnt;
//     fillRS: LDS off[] = base+rp, place via LDS atomicAdd only; cs writes
//             confined to XCD-local 400KB window (wgid&7==range).

#define DFEAT 128

typedef __attribute__((ext_vector_type(8))) short bf16x8;
typedef __attribute__((ext_vector_type(4))) float f32x4;

__device__ __forceinline__ unsigned short f2bf(float f) {
    unsigned u = __float_as_uint(f);
    u += 0x7fffu + ((u >> 16) & 1u);
    return (unsigned short)(u >> 16);
}
__device__ __forceinline__ float bf2f(unsigned short u) {
    return __uint_as_float((unsigned)u << 16);
}
__device__ __forceinline__ float4 bf4tof4(ushort4 u) {
    return make_float4(__uint_as_float((unsigned)u.x << 16),
                       __uint_as_float((unsigned)u.y << 16),
                       __uint_as_float((unsigned)u.z << 16),
                       __uint_as_float((unsigned)u.w << 16));
}
__device__ __forceinline__ unsigned f2h16(float f) {
    return (unsigned)__half_as_ushort(__float2half(f));
}
__device__ __forceinline__ float h16f(unsigned u) {
    return __half2float(__ushort_as_half((unsigned short)u));
}

// ---------------- atomic-free CSR build ----------------
constexpr int RANGES = 8;     // = XCD count; wgid & 7 -> XCD (round-robin)
constexpr int SLICES = 32;    // edge-stream slices
constexpr int MAXRSZ = 6400;  // >= ceil(N/RANGES); N=50000 -> 6250

// wgid = range + 8*(slice + SLICES*graph) -> 512 blocks
__global__ __launch_bounds__(256) void histRS_kernel(
    const int* __restrict__ dst1, const int* __restrict__ dst2,
    int* __restrict__ base, int n, int E, int rsz) {
    int range = blockIdx.x & (RANGES - 1);
    int q = blockIdx.x >> 3;
    int slice = q & (SLICES - 1);
    int graph = q >> 5;   // SLICES == 32
    const int* dst = graph ? dst2 : dst1;
    int r0 = range * rsz;
    int rn = min(rsz, n - r0);
    if (rn <= 0) return;
    __shared__ int hist[MAXRSZ];
    int t = threadIdx.x;
    for (int i = t; i < rn; i += 256) hist[i] = 0;
    __syncthreads();
    int es = (E + SLICES - 1) / SLICES;
    int e0 = slice * es;
    int e1 = min(e0 + es, E);
    for (int i = e0 + t; i < e1; i += 256) {
        unsigned d = (unsigned)(dst[i] - r0);
        if (d < (unsigned)rn) atomicAdd(&hist[d], 1);  // LDS atomic
    }
    __syncthreads();
    int* bp = base + (size_t)(graph * SLICES + slice) * n + r0;
    for (int i = t; i < rn; i += 256) bp[i] = hist[i];  // dense, exclusive
}

// per-node exclusive prefix across slices; emits per-node totals (cnt)
__global__ __launch_bounds__(256) void slicescan_kernel(
    int* __restrict__ base, int* __restrict__ cnt1, int* __restrict__ cnt2, int n) {
    int node = blockIdx.x * 256 + threadIdx.x;
    int g = blockIdx.y;
    if (node >= n) return;
    int* p = base + (size_t)g * SLICES * n + node;
    int run = 0;
#pragma unroll
    for (int s = 0; s < SLICES; ++s) {
        int v = p[(size_t)s * n];
        p[(size_t)s * n] = run;
        run += v;
    }
    (g ? cnt2 : cnt1)[node] = run;
}

__global__ __launch_bounds__(256) void fillRS_kernel(
    const int* __restrict__ src1, const int* __restrict__ dst1,
    const int* __restrict__ src2, const int* __restrict__ dst2,
    const int* __restrict__ base,
    const int* __restrict__ rp1, const int* __restrict__ rp2,
    const float* __restrict__ dv1, const float* __restrict__ dv2,
    int* __restrict__ cs1, int* __restrict__ cs2, int n, int E, int rsz) {
    int range = blockIdx.x & (RANGES - 1);
    int q = blockIdx.x >> 3;
    int slice = q & (SLICES - 1);
    int graph = q >> 5;
    const int *src, *dst, *rp;
    const float* dv;
    int* cs;
    if (graph == 0) { src = src1; dst = dst1; rp = rp1; dv = dv1; cs = cs1; }
    else            { src = src2; dst = dst2; rp = rp2; dv = dv2; cs = cs2; }
    int r0 = range * rsz;
    int rn = min(rsz, n - r0);
    if (rn <= 0) return;
    __shared__ int off[MAXRSZ];
    int t = threadIdx.x;
    const int* bp = base + (size_t)(graph * SLICES + slice) * n + r0;
    for (int i = t; i < rn; i += 256) off[i] = bp[i] + rp[r0 + i];
    __syncthreads();
    int es = (E + SLICES - 1) / SLICES;
    int e0 = slice * es;
    int e1 = min(e0 + es, E);
    for (int i = e0 + t; i < e1; i += 256) {
        int d = dst[i];
        unsigned dr = (unsigned)(d - r0);
        if (dr < (unsigned)rn) {
            int s = src[i];
            float w = dv[d] * dv[s];
            int pos = atomicAdd(&off[dr], 1);  // LDS atomic
            cs[pos] = (int)((f2h16(w) << 16) | (unsigned)s);  // {fp16 norm, src:16}
        }
    }
}

// ---------------- CSR scan (unchanged) ----------------
__global__ __launch_bounds__(256) void blocksum_kernel(const int* __restrict__ c1,
                                                       const int* __restrict__ c2,
                                                       int* __restrict__ bs, int n, int nb) {
    const int* c = blockIdx.y ? c2 : c1;
    int* out = bs + (size_t)blockIdx.y * nb;
    int t = threadIdx.x;
    int base = blockIdx.x * 2048 + t * 8;
    int s = 0;
#pragma unroll
    for (int i = 0; i < 8; ++i) {
        int idx = base + i;
        if (idx < n) s += c[idx];
    }
    __shared__ int red[256];
    red[t] = s;
    __syncthreads();
    for (int o = 128; o > 0; o >>= 1) {
        if (t < o) red[t] += red[t + o];
        __syncthreads();
    }
    if (t == 0) out[blockIdx.x] = red[0];
}

__global__ void scansums_kernel(int* __restrict__ bs, int nb, int* __restrict__ rp1,
                                int* __restrict__ rp2, int n, int E, float* __restrict__ stats) {
    int t = threadIdx.x;  // 64 threads
    if (t < 2) {
        int* b = bs + (size_t)t * nb;
        int run = 0;
        for (int i = 0; i < nb; ++i) {
            int v = b[i];
            b[i] = run;
            run += v;
        }
        (t ? rp2 : rp1)[n] = E;
    }
    for (int i = t; i < 512; i += 64) stats[i] = 0.f;
}

__global__ __launch_bounds__(256) void writerp_kernel(const int* __restrict__ c1,
                                                      const int* __restrict__ c2,
                                                      const int* __restrict__ bs,
                                                      int* __restrict__ rp1, int* __restrict__ rp2,
                                                      float* __restrict__ dv1,
                                                      float* __restrict__ dv2, int n, int nb) {
    const int* c = blockIdx.y ? c2 : c1;
    int* rp = blockIdx.y ? rp2 : rp1;
    float* dv = blockIdx.y ? dv2 : dv1;
    int boff = bs[(size_t)blockIdx.y * nb + blockIdx.x];
    int t = threadIdx.x;
    int base = blockIdx.x * 2048 + t * 8;
    int v[8];
    int s = 0;
#pragma unroll
    for (int i = 0; i < 8; ++i) {
        int idx = base + i;
        v[i] = (idx < n) ? c[idx] : 0;
        s += v[i];
    }
    __shared__ int red[256];
    red[t] = s;
    __syncthreads();
    for (int o = 1; o < 256; o <<= 1) {
        int x = (t >= o) ? red[t - o] : 0;
        __syncthreads();
        red[t] += x;
        __syncthreads();
    }
    int run = boff + red[t] - s;
#pragma unroll
    for (int i = 0; i < 8; ++i) {
        int idx = base + i;
        if (idx < n) {
            rp[idx] = run;
            dv[idx] = rsqrtf((float)(v[i] + 1));  // +1 self-loop
            run += v[i];
        }
    }
}

// ---------------- dual aggregation: one wave per node ----------------
template <int FV, typename OutT>
__global__ __launch_bounds__(256) void dualagg_kernel(
    const unsigned short* __restrict__ h1, const unsigned short* __restrict__ h2,
    const int* __restrict__ rp1, const int* __restrict__ cs1, const float* __restrict__ dv1,
    const int* __restrict__ rp2, const int* __restrict__ cs2, const float* __restrict__ dv2,
    const float* __restrict__ bias, OutT* __restrict__ o1, OutT* __restrict__ o2, int n) {
    constexpr int COLS = FV * 4;
    const unsigned short* h;
    const int *rp, *cs;
    const float* dv;
    OutT* out;
    if (blockIdx.y == 0) { h = h1; rp = rp1; cs = cs1; dv = dv1; out = o1; }
    else                 { h = h2; rp = rp2; cs = cs2; dv = dv2; out = o2; }
    int wid = blockIdx.x * 4 + (threadIdx.x >> 6);
    if (wid >= n) return;
    int lane = threadIdx.x & 63;
    int half = lane >> 5;
    int l = lane & 31;
    bool act = (l < FV);
    float4 acc = make_float4(0.f, 0.f, 0.f, 0.f);
    int e0 = rp[wid], e1 = rp[wid + 1];
    int e = e0 + half;
    for (; e + 6 < e1; e += 8) {
        int va = cs[e], vb = cs[e + 2], vc = cs[e + 4], vd = cs[e + 6];
        float wa = h16f((unsigned)va >> 16); int sa = va & 0xFFFF;
        float wb = h16f((unsigned)vb >> 16); int sb = vb & 0xFFFF;
        float wc = h16f((unsigned)vc >> 16); int sc = vc & 0xFFFF;
        float wd = h16f((unsigned)vd >> 16); int sd = vd & 0xFFFF;
        if (act) {
            float4 ha = bf4tof4(((const ushort4*)(h + (size_t)sa * COLS))[l]);
            float4 hb = bf4tof4(((const ushort4*)(h + (size_t)sb * COLS))[l]);
            float4 hc = bf4tof4(((const ushort4*)(h + (size_t)sc * COLS))[l]);
            float4 hd = bf4tof4(((const ushort4*)(h + (size_t)sd * COLS))[l]);
            acc.x = fmaf(wa, ha.x, acc.x); acc.y = fmaf(wa, ha.y, acc.y);
            acc.z = fmaf(wa, ha.z, acc.z); acc.w = fmaf(wa, ha.w, acc.w);
            acc.x = fmaf(wb, hb.x, acc.x); acc.y = fmaf(wb, hb.y, acc.y);
            acc.z = fmaf(wb, hb.z, acc.z); acc.w = fmaf(wb, hb.w, acc.w);
            acc.x = fmaf(wc, hc.x, acc.x); acc.y = fmaf(wc, hc.y, acc.y);
            acc.z = fmaf(wc, hc.z, acc.z); acc.w = fmaf(wc, hc.w, acc.w);
            acc.x = fmaf(wd, hd.x, acc.x); acc.y = fmaf(wd, hd.y, acc.y);
            acc.z = fmaf(wd, hd.z, acc.z); acc.w = fmaf(wd, hd.w, acc.w);
        }
    }
    for (; e < e1; e += 2) {
        int va = cs[e];
        float wa = h16f((unsigned)va >> 16); int sa = va & 0xFFFF;
        if (act) {
            float4 ha = bf4tof4(((const ushort4*)(h + (size_t)sa * COLS))[l]);
            acc.x = fmaf(wa, ha.x, acc.x); acc.y = fmaf(wa, ha.y, acc.y);
            acc.z = fmaf(wa, ha.z, acc.z); acc.w = fmaf(wa, ha.w, acc.w);
        }
    }
    acc.x += __shfl_xor(acc.x, 32);
    acc.y += __shfl_xor(acc.y, 32);
    acc.z += __shfl_xor(acc.z, 32);
    acc.w += __shfl_xor(acc.w, 32);
    if (half == 0 && act) {
        float dn = dv[wid];
        float w = dn * dn;  // self-loop norm
        float4 hv = bf4tof4(((const ushort4*)(h + (size_t)wid * COLS))[l]);
        acc.x = fmaf(w, hv.x, acc.x); acc.y = fmaf(w, hv.y, acc.y);
        acc.z = fmaf(w, hv.z, acc.z); acc.w = fmaf(w, hv.w, acc.w);
        float4 b = ((const float4*)bias)[l];
        acc.x += b.x; acc.y += b.y; acc.z += b.z; acc.w += b.w;
        if constexpr (sizeof(OutT) == 4) {
            ((float4*)((float*)out + (size_t)wid * COLS))[l] = acc;
        } else {
            ushort4 o;
            o.x = f2bf(acc.x); o.y = f2bf(acc.y); o.z = f2bf(acc.z); o.w = f2bf(acc.w);
            ((ushort4*)((unsigned short*)out + (size_t)wid * COLS))[l] = o;
        }
    }
}

// ---------------- Layer-1 quad GEMM ----------------
__global__ __launch_bounds__(256) void gemm_l1_kernel(
    const float* __restrict__ x1a, const float* __restrict__ x1b, const float* __restrict__ x2a,
    const float* __restrict__ x2b, const float* __restrict__ Wi, unsigned short* __restrict__ H1,
    unsigned short* __restrict__ H2, int nrows) {
    constexpr int CG = 16;
    const float* X = (blockIdx.y == 0) ? x1a : (blockIdx.y == 1) ? x1b
                     : (blockIdx.y == 2) ? x2a : x2b;
    const float* W = Wi + (blockIdx.y & 1) * 128 * 64;
    unsigned short* Y = (blockIdx.y < 2) ? H1 : H2;
    int ocol = (int)(blockIdx.y & 1) * 64;
    __shared__ float Ws[32][64];
    __shared__ float Xs[64][32];
    int tid = threadIdx.x;
    int row0 = blockIdx.x * 64;
    int cg = tid % CG;
    int rg = tid / CG;
    float4 acc[4];
#pragma unroll
    for (int i = 0; i < 4; ++i) acc[i] = make_float4(0.f, 0.f, 0.f, 0.f);
    for (int kc = 0; kc < 4; ++kc) {
        for (int i = tid; i < 32 * CG; i += 256) {
            int r = i / CG, c = i % CG;
            *(float4*)&Ws[r][c * 4] = *(const float4*)(W + (size_t)(kc * 32 + r) * 64 + c * 4);
        }
        for (int i = tid; i < 64 * 8; i += 256) {
            int r = i / 8, c = i % 8;
            int gr = row0 + r;
            float4 v = make_float4(0.f, 0.f, 0.f, 0.f);
            if (gr < nrows) v = *(const float4*)(X + (size_t)gr * DFEAT + kc * 32 + c * 4);
            *(float4*)&Xs[r][c * 4] = v;
        }
        __syncthreads();
#pragma unroll
        for (int k = 0; k < 32; ++k) {
            float4 w = *(float4*)&Ws[k][cg * 4];
#pragma unroll
            for (int i = 0; i < 4; ++i) {
                float a = Xs[rg * 4 + i][k];
                acc[i].x = fmaf(a, w.x, acc[i].x);
                acc[i].y = fmaf(a, w.y, acc[i].y);
                acc[i].z = fmaf(a, w.z, acc[i].z);
                acc[i].w = fmaf(a, w.w, acc[i].w);
            }
        }
        __syncthreads();
    }
#pragma unroll
    for (int i = 0; i < 4; ++i) {
        int r = row0 + rg * 4 + i;
        if (r < nrows) {
            ushort4 o;
            o.x = f2bf(acc[i].x); o.y = f2bf(acc[i].y);
            o.z = f2bf(acc[i].z); o.w = f2bf(acc[i].w);
            *(ushort4*)(Y + (size_t)r * DFEAT + ocol + cg * 4) = o;
        }
    }
}

// ---------------- prepW: Wm (2x128x128 fp32) -> bf16 transposed [l][kc][col][kk] ----------------
__global__ __launch_bounds__(256) void prepW_kernel(const float* __restrict__ Wm,
                                                    unsigned short* __restrict__ Wt) {
    int o = blockIdx.x * 256 + threadIdx.x;  // 16384 per layer
    int l = blockIdx.y;
    int kk = o & 31;
    int col = (o >> 5) & 127;
    int kc = o >> 12;
    int k = kc * 32 + kk;
    Wt[(size_t)l * 16384 + o] = f2bf(Wm[(size_t)l * 16384 + (size_t)k * 128 + col]);
}

// ---------------- MFMA fused GEMM (128->128): x = w1*relu(bn(A)) + w2*relu(bn(B)) ----------------
__global__ __launch_bounds__(256) void gemm_mfma_kernel(
    const unsigned short* __restrict__ Abf, const unsigned short* __restrict__ Bbf,
    const float* __restrict__ ss, const float* __restrict__ wout,
    const unsigned short* __restrict__ Wt, unsigned short* __restrict__ Y, int nrows) {
    __shared__ short Xs[64][128];
    int tid = threadIdx.x;
    int row0 = blockIdx.x * 64;
    int wave = tid >> 6, lane = tid & 63;
    int m = lane & 15, quad = lane >> 4;
    float w1 = wout[0], w2 = wout[1];
    for (int u = tid; u < 1024; u += 256) {
        int r = u >> 4;
        int col0 = (u & 15) * 8;
        int gr = row0 + r;
        if (gr < nrows) {
#pragma unroll
            for (int hh = 0; hh < 2; ++hh) {
                int c = col0 + hh * 4;
                float4 fa = bf4tof4(*(const ushort4*)(Abf + (size_t)gr * 128 + c));
                float4 fb = bf4tof4(*(const ushort4*)(Bbf + (size_t)gr * 128 + c));
                float4 sa = *(const float4*)(ss + c);
                float4 ha = *(const float4*)(ss + 128 + c);
                float4 sb = *(const float4*)(ss + 256 + c);
                float4 hb = *(const float4*)(ss + 384 + c);
                ushort4 o;
                o.x = f2bf(w1 * fmaxf(fmaf(fa.x, sa.x, ha.x), 0.f) +
                           w2 * fmaxf(fmaf(fb.x, sb.x, hb.x), 0.f));
                o.y = f2bf(w1 * fmaxf(fmaf(fa.y, sa.y, ha.y), 0.f) +
                           w2 * fmaxf(fmaf(fb.y, sb.y, hb.y), 0.f));
                o.z = f2bf(w1 * fmaxf(fmaf(fa.z, sa.z, ha.z), 0.f) +
                           w2 * fmaxf(fmaf(fb.z, sb.z, hb.z), 0.f));
                o.w = f2bf(w1 * fmaxf(fmaf(fa.w, sa.w, ha.w), 0.f) +
                           w2 * fmaxf(fmaf(fb.w, sb.w, hb.w), 0.f));
                *(ushort4*)&Xs[r][c] = o;
            }
        } else {
            ushort4 z = {0, 0, 0, 0};
            *(ushort4*)&Xs[r][col0] = z;
            *(ushort4*)&Xs[r][col0 + 4] = z;
        }
    }
    __syncthreads();
    f32x4 acc[8];
#pragma unroll
    for (int i = 0; i < 8; ++i) acc[i] = (f32x4){0.f, 0.f, 0.f, 0.f};
#pragma unroll
    for (int kc = 0; kc < 4; ++kc) {
        bf16x8 a = *(const bf16x8*)&Xs[wave * 16 + m][kc * 32 + quad * 8];
#pragma unroll
        for (int ct = 0; ct < 8; ++ct) {
            const short* bp = (const short*)(Wt + ((size_t)(kc * 128 + ct * 16 + m) * 32) + quad * 8);
            bf16x8 b = *(const bf16x8*)bp;
            acc[ct] = __builtin_amdgcn_mfma_f32_16x16x32_bf16(a, b, acc[ct], 0, 0, 0);
        }
    }
#pragma unroll
    for (int ct = 0; ct < 8; ++ct) {
#pragma unroll
        for (int i = 0; i < 4; ++i) {
            int gr = row0 + wave * 16 + quad * 4 + i;
            if (gr < nrows) Y[(size_t)gr * 128 + ct * 16 + m] = f2bf(acc[ct][i]);
        }
    }
}

// ---------------- VALU fused GEMM (final 128->40) ----------------
template <int CG, int RPT>
__global__ __launch_bounds__(256) void gemm_fused_kernel(
    const unsigned short* __restrict__ Abf, const unsigned short* __restrict__ Bbf,
    const float* __restrict__ ss, const float* __restrict__ wout, const float* __restrict__ W,
    unsigned short* __restrict__ Y, int nrows, int fout, int ostride) {
    __shared__ float Ws[32][CG * 4];
    __shared__ float Xs[64][32];
    int tid = threadIdx.x;
    int row0 = blockIdx.x * 64;
    int cg = tid % CG;
    int rg = tid / CG;
    float w1 = wout[0], w2 = wout[1];
    float4 acc[RPT];
#pragma unroll
    for (int i = 0; i < RPT; ++i) acc[i] = make_float4(0.f, 0.f, 0.f, 0.f);
    for (int kc = 0; kc < 4; ++kc) {
        for (int i = tid; i < 32 * CG; i += 256) {
            int r = i / CG, c = i % CG;
            float4 w;
            if ((c * 4 + 3) < fout) {
                w = *(const float4*)(W + (size_t)(kc * 32 + r) * fout + c * 4);
            } else {
                float t0 = (c * 4 + 0) < fout ? W[(size_t)(kc * 32 + r) * fout + c * 4 + 0] : 0.f;
                float t1 = (c * 4 + 1) < fout ? W[(size_t)(kc * 32 + r) * fout + c * 4 + 1] : 0.f;
                float t2 = (c * 4 + 2) < fout ? W[(size_t)(kc * 32 + r) * fout + c * 4 + 2] : 0.f;
                float t3 = (c * 4 + 3) < fout ? W[(size_t)(kc * 32 + r) * fout + c * 4 + 3] : 0.f;
                w = make_float4(t0, t1, t2, t3);
            }
            *(float4*)&Ws[r][c * 4] = w;
        }
        for (int i = tid; i < 64 * 8; i += 256) {
            int r = i / 8, c = i % 8;
            int gr = row0 + r;
            int col0 = kc * 32 + c * 4;
            float4 v = make_float4(0.f, 0.f, 0.f, 0.f);
            if (gr < nrows) {
                float4 a = bf4tof4(*(const ushort4*)(Abf + (size_t)gr * DFEAT + col0));
                float4 b = bf4tof4(*(const ushort4*)(Bbf + (size_t)gr * DFEAT + col0));
                float4 scA = *(const float4*)(ss + col0);
                float4 shA = *(const float4*)(ss + DFEAT + col0);
                float4 scB = *(const float4*)(ss + 2 * DFEAT + col0);
                float4 shB = *(const float4*)(ss + 3 * DFEAT + col0);
                v.x = w1 * fmaxf(fmaf(a.x, scA.x, shA.x), 0.f) +
                      w2 * fmaxf(fmaf(b.x, scB.x, shB.x), 0.f);
                v.y = w1 * fmaxf(fmaf(a.y, scA.y, shA.y), 0.f) +
                      w2 * fmaxf(fmaf(b.y, scB.y, shB.y), 0.f);
                v.z = w1 * fmaxf(fmaf(a.z, scA.z, shA.z), 0.f) +
                      w2 * fmaxf(fmaf(b.z, scB.z, shB.z), 0.f);
                v.w = w1 * fmaxf(fmaf(a.w, scA.w, shA.w), 0.f) +
                      w2 * fmaxf(fmaf(b.w, scB.w, shB.w), 0.f);
            }
            *(float4*)&Xs[r][c * 4] = v;
        }
        __syncthreads();
#pragma unroll
        for (int k = 0; k < 32; ++k) {
            float4 w = *(float4*)&Ws[k][cg * 4];
#pragma unroll
            for (int i = 0; i < RPT; ++i) {
                float a = Xs[rg * RPT + i][k];
                acc[i].x = fmaf(a, w.x, acc[i].x);
                acc[i].y = fmaf(a, w.y, acc[i].y);
                acc[i].z = fmaf(a, w.z, acc[i].z);
                acc[i].w = fmaf(a, w.w, acc[i].w);
            }
        }
        __syncthreads();
    }
    if (cg * 4 < fout) {
#pragma unroll
        for (int i = 0; i < RPT; ++i) {
            int r = row0 + rg * RPT + i;
            if (r < nrows) {
                ushort4 o;
                o.x = f2bf(acc[i].x); o.y = f2bf(acc[i].y);
                o.z = f2bf(acc[i].z); o.w = f2bf(acc[i].w);
                *(ushort4*)(Y + (size_t)r * ostride + cg * 4) = o;
            }
        }
    }
}

// ---------------- BN statistics: 2-level atomicAdd ----------------
__global__ __launch_bounds__(256) void stats2_kernel(const unsigned short* __restrict__ A,
                                                     const unsigned short* __restrict__ B,
                                                     float* __restrict__ stats, int nrows) {
    __shared__ float red1[256];
    __shared__ float red2[256];
    int t = threadIdx.x;
    int col = t & 127;
    int rg = t >> 7;
    const unsigned short* src = (blockIdx.y == 0) ? A : B;
    float* st = stats + (size_t)blockIdx.y * 256;
    int r0 = blockIdx.x * 128 + rg * 64;
    int r1 = min(r0 + 64, nrows);
    float s = 0.f, s2 = 0.f;
    for (int r = r0; r < r1; ++r) {
        float v = bf2f(src[(size_t)r * DFEAT + col]);
        s += v;
        s2 = fmaf(v, v, s2);
    }
    red1[t] = s;
    red2[t] = s2;
    __syncthreads();
    if (t < 128) {
        atomicAdd(&st[col], red1[t] + red1[t + 128]);
        atomicAdd(&st[DFEAT + col], red2[t] + red2[t + 128]);
    }
}

// ---------------- BN scale/shift + gates; zeros stats for next layer ----------------
__global__ __launch_bounds__(128) void gate_prep_kernel(
    float* __restrict__ statsA, float* __restrict__ statsB,
    const unsigned short* __restrict__ preA, const unsigned short* __restrict__ preB,
    const float* __restrict__ gamma, const float* __restrict__ beta,
    const float* __restrict__ gwA, const float* __restrict__ gbA,
    const float* __restrict__ gwB, const float* __restrict__ gbB,
    float* __restrict__ ss, float* __restrict__ wout, int nrows) {
    __shared__ float red[128];
    __shared__ float dotA_s;
    int t = threadIdx.x;
    float invN = 1.f / (float)nrows;
    float meanA = statsA[t] * invN;
    float varA = statsA[DFEAT + t] * invN - meanA * meanA;
    float scA = gamma[t] * rsqrtf(varA + 1e-5f);
    float shA = beta[t] - meanA * scA;
    ss[t] = scA;
    ss[DFEAT + t] = shA;
    float meanB = statsB[t] * invN;
    float varB = statsB[DFEAT + t] * invN - meanB * meanB;
    float scB = gamma[t] * rsqrtf(varB + 1e-5f);
    float shB = beta[t] - meanB * scB;
    ss[2 * DFEAT + t] = scB;
    ss[3 * DFEAT + t] = shB;
    statsA[t] = 0.f;
    statsA[DFEAT + t] = 0.f;
    statsB[t] = 0.f;
    statsB[DFEAT + t] = 0.f;
    float av = fmaxf(fmaf(bf2f(preA[(size_t)(nrows - 1) * DFEAT + t]), scA, shA), 0.f);
    red[t] = av * gwA[t];
    __syncthreads();
    for (int s = 64; s > 0; s >>= 1) {
        if (t < s) red[t] += red[t + s];
        __syncthreads();
    }
    if (t == 0) dotA_s = red[0];
    __syncthreads();
    float bv = fmaxf(fmaf(bf2f(preB[(size_t)(nrows - 1) * DFEAT + t]), scB, shB), 0.f);
    red[t] = bv * gwB[t];
    __syncthreads();
    for (int s = 64; s > 0; s >>= 1) {
        if (t < s) red[t] += red[t + s];
        __syncthreads();
    }
    if (t == 0) {
        float s1 = 1.f / (1.f + expf(-(dotA_s + gbA[0])));
        float s2 = 1.f / (1.f + expf(-(red[0] + gbB[0])));
        float tt = s1 + s2;
        wout[0] = s1 / tt;
        wout[1] = s2 / tt;
    }
}

__global__ __launch_bounds__(64) void gate_final_kernel(
    const float* __restrict__ p1, const float* __restrict__ p2,
    const float* __restrict__ w1v, const float* __restrict__ b1,
    const float* __restrict__ w2v, const float* __restrict__ b2,
    float* __restrict__ wout, int nrows, int nclass) {
    __shared__ float red[64];
    __shared__ float dot1_s;
    int t = threadIdx.x;
    float v = (t < nclass) ? p1[(size_t)(nrows - 1) * nclass + t] * w1v[t] : 0.f;
    red[t] = v;
    __syncthreads();
    for (int s = 32; s > 0; s >>= 1) {
        if (t < s) red[t] += red[t + s];
        __syncthreads();
    }
    if (t == 0) dot1_s = red[0];
    __syncthreads();
    v = (t < nclass) ? p2[(size_t)(nrows - 1) * nclass + t] * w2v[t] : 0.f;
    red[t] = v;
    __syncthreads();
    for (int s = 32; s > 0; s >>= 1) {
        if (t < s) red[t] += red[t + s];
        __syncthreads();
    }
    if (t == 0) {
        float s1 = 1.f / (1.f + expf(-(dot1_s + b1[0])));
        float s2 = 1.f / (1.f + expf(-(red[0] + b2[0])));
        float tt = s1 + s2;
        wout[0] = s1 / tt;
        wout[1] = s2 / tt;
    }
}

__global__ __launch_bounds__(256) void mix_kernel(const float* __restrict__ p1,
                                                  const float* __restrict__ p2,
                                                  const float* __restrict__ wout,
                                                  float* __restrict__ o, int n4) {
    int idx = blockIdx.x * blockDim.x + threadIdx.x;
    if (idx >= n4) return;
    float w1 = wout[0], w2 = wout[1];
    float4 a = *(const float4*)(p1 + (size_t)idx * 4);
    float4 b = *(const float4*)(p2 + (size_t)idx * 4);
    float4 r = make_float4(w1 * a.x + w2 * b.x, w1 * a.y + w2 * b.y, w1 * a.z + w2 * b.z,
                           w1 * a.w + w2 * b.w);
    *(float4*)(o + (size_t)idx * 4) = r;
}

extern "C" void kernel_launch(void* const* d_in, const int* in_sizes, int n_in, void* d_out,
                              int out_size, void* d_ws, size_t ws_size, hipStream_t stream) {
    (void)n_in; (void)out_size; (void)ws_size;
    const int N = in_sizes[0] / DFEAT;        // 50000
    const int E = in_sizes[4] / 2;            // 800000
    const int NC = in_sizes[15];              // 40

    const float* x1a = (const float*)d_in[0];
    const float* x1b = (const float*)d_in[1];
    const float* x2a = (const float*)d_in[2];
    const float* x2b = (const float*)d_in[3];
    const int* ei1 = (const int*)d_in[4];
    const int* ei2 = (const int*)d_in[5];
    const float* Wi = (const float*)d_in[6];
    const float* bi = (const float*)d_in[7];
    const float* gi = (const float*)d_in[8];
    const float* bei = (const float*)d_in[9];
    const float* Wm = (const float*)d_in[10];
    const float* bm = (const float*)d_in[11];
    const float* gm = (const float*)d_in[12];
    const float* bem = (const float*)d_in[13];
    const float* Wf = (const float*)d_in[14];
    const float* bf = (const float*)d_in[15];
    const float* fc1w1_W = (const float*)d_in[16];
    const float* fc1w1_b = (const float*)d_in[17];
    const float* fc1w2_W = (const float*)d_in[18];
    const float* fc1w2_b = (const float*)d_in[19];
    const float* aws_w1_W = (const float*)d_in[20];
    const float* aws_w1_b = (const float*)d_in[21];
    const float* aws_w2_W = (const float*)d_in[22];
    const float* aws_w2_b = (const float*)d_in[23];
    const float* fcw1_W = (const float*)d_in[24];
    const float* fcw1_b = (const float*)d_in[25];
    const float* fcw2_W = (const float*)d_in[26];
    const float* fcw2_b = (const float*)d_in[27];

    char* ws = (char*)d_ws;
    size_t off = 0;
    auto alloc = [&](size_t bytes) -> char* {
        char* p = ws + off;
        off += (bytes + 255) & ~(size_t)255;
        return p;
    };
    unsigned short* A = (unsigned short*)alloc((size_t)N * DFEAT * 2);
    unsigned short* B = (unsigned short*)alloc((size_t)N * DFEAT * 2);
    unsigned short* H1 = (unsigned short*)alloc((size_t)N * DFEAT * 2);
    unsigned short* H2 = (unsigned short*)alloc((size_t)N * DFEAT * 2);
    int* rp1 = (int*)alloc((size_t)(N + 1) * 4);
    int* rp2 = (int*)alloc((size_t)(N + 1) * 4);
    int* cnt1 = (int*)alloc((size_t)N * 4);
    int* cnt2 = (int*)alloc((size_t)N * 4);
    float* dv1 = (float*)alloc((size_t)N * 4);
    float* dv2 = (float*)alloc((size_t)N * 4);
    int* cs1 = (int*)alloc((size_t)E * 4);
    int* cs2 = (int*)alloc((size_t)E * 4);
    int* base = (int*)alloc((size_t)2 * SLICES * N * 4);  // 12.8 MB
    unsigned short* Wt = (unsigned short*)alloc((size_t)2 * 16384 * 2);
    float* stats = (float*)alloc(2048);
    float* statsA = stats;
    float* statsB = stats + 256;
    float* ssbuf = (float*)alloc(2048);
    float* wout = (float*)alloc(256);
    int nb = (N + 2047) / 2048;  // 25
    int* bsums = (int*)alloc((size_t)2 * nb * 4);

    const int* src1 = ei1;
    const int* dst1 = ei1 + E;
    const int* src2 = ei2;
    const int* dst2 = ei2 + E;

    int rsz = (N + RANGES - 1) / RANGES;      // 6250 (<= MAXRSZ)
    int gemmbl = (N + 63) / 64;
    dim3 rsgrid(RANGES * SLICES * 2);         // 512 blocks, wgid&7 == range
    dim3 ssgrid((N + 255) / 256, 2);
    dim3 agggrid((N + 3) / 4, 2);
    dim3 statgrid((N + 127) / 128, 2);
    dim3 scangrid(nb, 2);
    dim3 l1grid(gemmbl, 4);
    dim3 prepgrid(64, 2);

    // ---- CSR build (atomic-free counting sort) + weight prep ----
    prepW_kernel<<<prepgrid, 256, 0, stream>>>(Wm, Wt);
    histRS_kernel<<<rsgrid, 256, 0, stream>>>(dst1, dst2, base, N, E, rsz);
    slicescan_kernel<<<ssgrid, 256, 0, stream>>>(base, cnt1, cnt2, N);
    blocksum_kernel<<<scangrid, 256, 0, stream>>>(cnt1, cnt2, bsums, N, nb);
    scansums_kernel<<<1, 64, 0, stream>>>(bsums, nb, rp1, rp2, N, E, stats);
    writerp_kernel<<<scangrid, 256, 0, stream>>>(cnt1, cnt2, bsums, rp1, rp2, dv1, dv2, N, nb);
    fillRS_kernel<<<rsgrid, 256, 0, stream>>>(src1, dst1, src2, dst2, base, rp1, rp2,
                                              dv1, dv2, cs1, cs2, N, E, rsz);

    // ---- Layer 1 ----
    gemm_l1_kernel<<<l1grid, 256, 0, stream>>>(x1a, x1b, x2a, x2b, Wi, H1, H2, N);
    dualagg_kernel<32, unsigned short><<<agggrid, 256, 0, stream>>>(
        H1, H2, rp1, cs1, dv1, rp2, cs2, dv2, bi, A, B, N);
    stats2_kernel<<<statgrid, 256, 0, stream>>>(A, B, stats, N);
    gate_prep_kernel<<<1, 128, 0, stream>>>(statsA, statsB, A, B, gi, bei, fc1w1_W, fc1w1_b,
                                            fc1w2_W, fc1w2_b, ssbuf, wout, N);

    // ---- Middle layer 0 (MFMA fused GEMM) ----
    gemm_mfma_kernel<<<gemmbl, 256, 0, stream>>>(A, B, ssbuf, wout, Wt, H1, N);
    dualagg_kernel<32, unsigned short><<<agggrid, 256, 0, stream>>>(
        H1, H1, rp1, cs1, dv1, rp2, cs2, dv2, bm, A, B, N);
    stats2_kernel<<<statgrid, 256, 0, stream>>>(A, B, stats, N);
    gate_prep_kernel<<<1, 128, 0, stream>>>(statsA, statsB, A, B, gm, bem, aws_w1_W, aws_w1_b,
                                            aws_w2_W, aws_w2_b, ssbuf, wout, N);

    // ---- Middle layer 1 ----
    gemm_mfma_kernel<<<gemmbl, 256, 0, stream>>>(A, B, ssbuf, wout, Wt + 16384, H1, N);
    dualagg_kernel<32, unsigned short><<<agggrid, 256, 0, stream>>>(
        H1, H1, rp1, cs1, dv1, rp2, cs2, dv2, bm + 128, A, B, N);
    stats2_kernel<<<statgrid, 256, 0, stream>>>(A, B, stats, N);
    gate_prep_kernel<<<1, 128, 0, stream>>>(statsA, statsB, A, B, gm + 128, bem + 128,
                                            aws_w1_W + 128, aws_w1_b + 1, aws_w2_W + 128,
                                            aws_w2_b + 1, ssbuf, wout, N);

    // ---- Final layer ----
    float* out0 = (float*)d_out;
    float* p1 = out0 + (size_t)N * NC;
    float* p2 = out0 + (size_t)2 * N * NC;
    gemm_fused_kernel<16, 4><<<gemmbl, 256, 0, stream>>>(A, B, ssbuf, wout, Wf, H2, N, NC, NC);
    dualagg_kernel<10, float><<<agggrid, 256, 0, stream>>>(H2, H2, rp1, cs1, dv1, rp2, cs2, dv2,
                                                           bf, p1, p2, N);
    gate_final_kernel<<<1, 64, 0, stream>>>(p1, p2, fcw1_W, fcw1_b, fcw2_W, fcw2_b, wout, N, NC);
    mix_kernel<<<(N * NC / 4 + 255) / 256, 256, 0, stream>>>(p1, p2, wout, out0, N * NC / 4);
}

// Round 5
// 688.624 us; speedup vs baseline: 1.2895x; 1.1001x over previous
//
#include <hip/hip_runtime.h>
#include <hip/hip_fp16.h>

// CLAGCN forward on MI355X.
// R1-R6: see history. R7 (FAILED): LDS bucket sort, barrier-latency-bound.
// R8/R9: dst-range partition; WRITE stuck ~80MB -> global-atomic theory.
// R10: atomic-free counting sort confirmed atomics were the WRITE traffic
//     (83->24MB) but kept 8x edge re-read + 512-block grid (20% occ,
//     VALU 6%) -> fillRS still 89us. CSR build ~150us total.
// R11: two-level counting sort, each edge touched O(1) times:
//     partA: read edges ONCE, bin by dst>>13 into per-(g,range) packed
//            streams {dloc:13,src:16} via LDS compaction; only ~5K global
//            atomics (one per range per block for reservation).
//     histB: 32KB LDS hist per (range,sub) over stream -> dense baseB.
//     scanB: prefix over subs -> cnt (feeds existing rp/dv pipeline).
//     fillC: off=baseB+rp in LDS, place via LDS atomics, dense cs writes.

#define DFEAT 128

typedef __attribute__((ext_vector_type(8))) short bf16x8;
typedef __attribute__((ext_vector_type(4))) float f32x4;

__device__ __forceinline__ unsigned short f2bf(float f) {
    unsigned u = __float_as_uint(f);
    u += 0x7fffu + ((u >> 16) & 1u);
    return (unsigned short)(u >> 16);
}
__device__ __forceinline__ float bf2f(unsigned short u) {
    return __uint_as_float((unsigned)u << 16);
}
__device__ __forceinline__ float4 bf4tof4(ushort4 u) {
    return make_float4(__uint_as_float((unsigned)u.x << 16),
                       __uint_as_float((unsigned)u.y << 16),
                       __uint_as_float((unsigned)u.z << 16),
                       __uint_as_float((unsigned)u.w << 16));
}
__device__ __forceinline__ unsigned f2h16(float f) {
    return (unsigned)__half_as_ushort(__float2half(f));
}
__device__ __forceinline__ float h16f(unsigned u) {
    return __half2float(__ushort_as_half((unsigned short)u));
}

// ---------------- two-level counting-sort CSR build ----------------
constexpr int RSH = 13;        // range shift -> 8192 nodes per range
constexpr int RSZ = 8192;
constexpr int NRMAX = 8;       // max ranges (N <= 65536)
constexpr int EPA = 2048;      // edges per partition block
constexpr int SUBS = 16;       // sub-slices per range for hist/fill
constexpr int SCAP = 160000;   // stream capacity per (graph, range)

// Phase A: single-pass edge partition into per-(g,range) streams.
__global__ __launch_bounds__(256) void partA_kernel(
    const int* __restrict__ src1, const int* __restrict__ dst1,
    const int* __restrict__ src2, const int* __restrict__ dst2,
    int* __restrict__ stg, int* __restrict__ gcount, int E, int nr) {
    int g = blockIdx.y;
    const int* src = g ? src2 : src1;
    const int* dst = g ? dst2 : dst1;
    __shared__ int buf[EPA];   // packed (d<<16)|s in load order
    __shared__ int buf2[EPA];  // binned by range
    __shared__ int cnt8[NRMAX + 1], pre8[NRMAX + 1], base8[NRMAX];
    int t = threadIdx.x;
    if (t < NRMAX) cnt8[t] = 0;
    __syncthreads();
    int e0 = blockIdx.x * EPA;
    int e1 = min(e0 + EPA, E);
    int ec = e1 - e0;
    // pass 1: load + count
    for (int i = e0 + t; i < e1; i += 256) {
        int d = dst[i];
        int s = src[i];
        buf[i - e0] = (d << 16) | s;  // d,s < 65536
        atomicAdd(&cnt8[d >> RSH], 1);
    }
    __syncthreads();
    if (t == 0) {
        int run = 0;
        for (int r = 0; r < nr; ++r) { pre8[r] = run; run += cnt8[r]; }
        pre8[nr] = run;
    }
    __syncthreads();
    if (t < nr) {
        base8[t] = atomicAdd(&gcount[g * NRMAX + t], cnt8[t]);
        cnt8[t] = 0;
    }
    __syncthreads();
    // pass 2: bin into buf2 (payload {dloc:13, src:16})
    for (int j = t; j < ec; j += 256) {
        int v = buf[j];
        int d = (unsigned)v >> 16;
        int r = d >> RSH;
        int p = pre8[r] + atomicAdd(&cnt8[r], 1);
        buf2[p] = ((d & (RSZ - 1)) << 16) | (v & 0xFFFF);
    }
    __syncthreads();
    // pass 3: dense run writes to streams
    for (int j = t; j < ec; j += 256) {
        int r = 0;
        while (j >= pre8[r + 1]) ++r;
        int gpos = base8[r] + (j - pre8[r]);
        if (gpos < SCAP) stg[((size_t)g * NRMAX + r) * SCAP + gpos] = buf2[j];
    }
}

// Phase B: per-(range,sub) LDS histogram -> dense baseB table.
__global__ __launch_bounds__(256) void histB_kernel(
    const int* __restrict__ stg, const int* __restrict__ gcount,
    int* __restrict__ baseB, int nr) {
    int g = blockIdx.y;
    int r = blockIdx.x / SUBS;
    int sub = blockIdx.x % SUBS;
    __shared__ int hist[RSZ];
    int t = threadIdx.x;
    for (int i = t; i < RSZ; i += 256) hist[i] = 0;
    __syncthreads();
    int len = min(gcount[g * NRMAX + r], SCAP);
    int seg = (len + SUBS - 1) / SUBS;
    int e0 = sub * seg, e1 = min(e0 + seg, len);
    const int* sp = stg + ((size_t)g * NRMAX + r) * SCAP;
    for (int i = e0 + t; i < e1; i += 256) atomicAdd(&hist[(unsigned)sp[i] >> 16], 1);
    __syncthreads();
    int* bp = baseB + (((size_t)(g * NRMAX + r) * SUBS + sub) << RSH);
    for (int i = t; i < RSZ; i += 256) bp[i] = hist[i];
}

// per-node exclusive prefix over subs; emits per-node totals (cnt).
__global__ __launch_bounds__(256) void scanB_kernel(
    int* __restrict__ baseB, int* __restrict__ cnt1, int* __restrict__ cnt2, int n) {
    int node = blockIdx.x * 256 + threadIdx.x;
    int g = blockIdx.y;
    if (node >= n) return;
    int r = node >> RSH, dloc = node & (RSZ - 1);
    int* p = baseB + (((size_t)(g * NRMAX + r) * SUBS) << RSH) + dloc;
    int run = 0;
#pragma unroll
    for (int s = 0; s < SUBS; ++s) {
        int v = p[(size_t)s << RSH];
        p[(size_t)s << RSH] = run;
        run += v;
    }
    (g ? cnt2 : cnt1)[node] = run;
}

// Phase C: final CSR placement; LDS atomics only, dense stream reads.
__global__ __launch_bounds__(256) void fillC_kernel(
    const int* __restrict__ stg, const int* __restrict__ gcount,
    const int* __restrict__ baseB,
    const int* __restrict__ rp1, const int* __restrict__ rp2,
    const float* __restrict__ dv1, const float* __restrict__ dv2,
    int* __restrict__ cs1, int* __restrict__ cs2, int n, int nr) {
    int g = blockIdx.y;
    int r = blockIdx.x / SUBS;
    int sub = blockIdx.x % SUBS;
    const int* rp = g ? rp2 : rp1;
    const float* dv = g ? dv2 : dv1;
    int* cs = g ? cs2 : cs1;
    __shared__ int off[RSZ];
    int t = threadIdx.x;
    int r0 = r << RSH;
    int rn = min(RSZ, n - r0);
    if (rn <= 0) return;
    const int* bp = baseB + (((size_t)(g * NRMAX + r) * SUBS + sub) << RSH);
    for (int i = t; i < rn; i += 256) off[i] = bp[i] + rp[r0 + i];
    __syncthreads();
    int len = min(gcount[g * NRMAX + r], SCAP);
    int seg = (len + SUBS - 1) / SUBS;
    int e0 = sub * seg, e1 = min(e0 + seg, len);
    const int* sp = stg + ((size_t)g * NRMAX + r) * SCAP;
    for (int i = e0 + t; i < e1; i += 256) {
        int v = sp[i];
        int dloc = (unsigned)v >> 16;
        int s = v & 0xFFFF;
        float w = dv[r0 + dloc] * dv[s];
        int pos = atomicAdd(&off[dloc], 1);  // LDS atomic
        cs[pos] = (int)((f2h16(w) << 16) | (unsigned)s);  // {fp16 norm, src:16}
    }
}

// ---------------- CSR scan (unchanged) ----------------
__global__ __launch_bounds__(256) void blocksum_kernel(const int* __restrict__ c1,
                                                       const int* __restrict__ c2,
                                                       int* __restrict__ bs, int n, int nb) {
    const int* c = blockIdx.y ? c2 : c1;
    int* out = bs + (size_t)blockIdx.y * nb;
    int t = threadIdx.x;
    int base = blockIdx.x * 2048 + t * 8;
    int s = 0;
#pragma unroll
    for (int i = 0; i < 8; ++i) {
        int idx = base + i;
        if (idx < n) s += c[idx];
    }
    __shared__ int red[256];
    red[t] = s;
    __syncthreads();
    for (int o = 128; o > 0; o >>= 1) {
        if (t < o) red[t] += red[t + o];
        __syncthreads();
    }
    if (t == 0) out[blockIdx.x] = red[0];
}

__global__ void scansums_kernel(int* __restrict__ bs, int nb, int* __restrict__ rp1,
                                int* __restrict__ rp2, int n, int E, float* __restrict__ stats) {
    int t = threadIdx.x;  // 64 threads
    if (t < 2) {
        int* b = bs + (size_t)t * nb;
        int run = 0;
        for (int i = 0; i < nb; ++i) {
            int v = b[i];
            b[i] = run;
            run += v;
        }
        (t ? rp2 : rp1)[n] = E;
    }
    for (int i = t; i < 512; i += 64) stats[i] = 0.f;
}

__global__ __launch_bounds__(256) void writerp_kernel(const int* __restrict__ c1,
                                                      const int* __restrict__ c2,
                                                      const int* __restrict__ bs,
                                                      int* __restrict__ rp1, int* __restrict__ rp2,
                                                      float* __restrict__ dv1,
                                                      float* __restrict__ dv2, int n, int nb) {
    const int* c = blockIdx.y ? c2 : c1;
    int* rp = blockIdx.y ? rp2 : rp1;
    float* dv = blockIdx.y ? dv2 : dv1;
    int boff = bs[(size_t)blockIdx.y * nb + blockIdx.x];
    int t = threadIdx.x;
    int base = blockIdx.x * 2048 + t * 8;
    int v[8];
    int s = 0;
#pragma unroll
    for (int i = 0; i < 8; ++i) {
        int idx = base + i;
        v[i] = (idx < n) ? c[idx] : 0;
        s += v[i];
    }
    __shared__ int red[256];
    red[t] = s;
    __syncthreads();
    for (int o = 1; o < 256; o <<= 1) {
        int x = (t >= o) ? red[t - o] : 0;
        __syncthreads();
        red[t] += x;
        __syncthreads();
    }
    int run = boff + red[t] - s;
#pragma unroll
    for (int i = 0; i < 8; ++i) {
        int idx = base + i;
        if (idx < n) {
            rp[idx] = run;
            dv[idx] = rsqrtf((float)(v[i] + 1));  // +1 self-loop
            run += v[i];
        }
    }
}

// ---------------- dual aggregation: one wave per node ----------------
template <int FV, typename OutT>
__global__ __launch_bounds__(256) void dualagg_kernel(
    const unsigned short* __restrict__ h1, const unsigned short* __restrict__ h2,
    const int* __restrict__ rp1, const int* __restrict__ cs1, const float* __restrict__ dv1,
    const int* __restrict__ rp2, const int* __restrict__ cs2, const float* __restrict__ dv2,
    const float* __restrict__ bias, OutT* __restrict__ o1, OutT* __restrict__ o2, int n) {
    constexpr int COLS = FV * 4;
    const unsigned short* h;
    const int *rp, *cs;
    const float* dv;
    OutT* out;
    if (blockIdx.y == 0) { h = h1; rp = rp1; cs = cs1; dv = dv1; out = o1; }
    else                 { h = h2; rp = rp2; cs = cs2; dv = dv2; out = o2; }
    int wid = blockIdx.x * 4 + (threadIdx.x >> 6);
    if (wid >= n) return;
    int lane = threadIdx.x & 63;
    int half = lane >> 5;
    int l = lane & 31;
    bool act = (l < FV);
    float4 acc = make_float4(0.f, 0.f, 0.f, 0.f);
    int e0 = rp[wid], e1 = rp[wid + 1];
    int e = e0 + half;
    for (; e + 6 < e1; e += 8) {
        int va = cs[e], vb = cs[e + 2], vc = cs[e + 4], vd = cs[e + 6];
        float wa = h16f((unsigned)va >> 16); int sa = va & 0xFFFF;
        float wb = h16f((unsigned)vb >> 16); int sb = vb & 0xFFFF;
        float wc = h16f((unsigned)vc >> 16); int sc = vc & 0xFFFF;
        float wd = h16f((unsigned)vd >> 16); int sd = vd & 0xFFFF;
        if (act) {
            float4 ha = bf4tof4(((const ushort4*)(h + (size_t)sa * COLS))[l]);
            float4 hb = bf4tof4(((const ushort4*)(h + (size_t)sb * COLS))[l]);
            float4 hc = bf4tof4(((const ushort4*)(h + (size_t)sc * COLS))[l]);
            float4 hd = bf4tof4(((const ushort4*)(h + (size_t)sd * COLS))[l]);
            acc.x = fmaf(wa, ha.x, acc.x); acc.y = fmaf(wa, ha.y, acc.y);
            acc.z = fmaf(wa, ha.z, acc.z); acc.w = fmaf(wa, ha.w, acc.w);
            acc.x = fmaf(wb, hb.x, acc.x); acc.y = fmaf(wb, hb.y, acc.y);
            acc.z = fmaf(wb, hb.z, acc.z); acc.w = fmaf(wb, hb.w, acc.w);
            acc.x = fmaf(wc, hc.x, acc.x); acc.y = fmaf(wc, hc.y, acc.y);
            acc.z = fmaf(wc, hc.z, acc.z); acc.w = fmaf(wc, hc.w, acc.w);
            acc.x = fmaf(wd, hd.x, acc.x); acc.y = fmaf(wd, hd.y, acc.y);
            acc.z = fmaf(wd, hd.z, acc.z); acc.w = fmaf(wd, hd.w, acc.w);
        }
    }
    for (; e < e1; e += 2) {
        int va = cs[e];
        float wa = h16f((unsigned)va >> 16); int sa = va & 0xFFFF;
        if (act) {
            float4 ha = bf4tof4(((const ushort4*)(h + (size_t)sa * COLS))[l]);
            acc.x = fmaf(wa, ha.x, acc.x); acc.y = fmaf(wa, ha.y, acc.y);
            acc.z = fmaf(wa, ha.z, acc.z); acc.w = fmaf(wa, ha.w, acc.w);
        }
    }
    acc.x += __shfl_xor(acc.x, 32);
    acc.y += __shfl_xor(acc.y, 32);
    acc.z += __shfl_xor(acc.z, 32);
    acc.w += __shfl_xor(acc.w, 32);
    if (half == 0 && act) {
        float dn = dv[wid];
        float w = dn * dn;  // self-loop norm
        float4 hv = bf4tof4(((const ushort4*)(h + (size_t)wid * COLS))[l]);
        acc.x = fmaf(w, hv.x, acc.x); acc.y = fmaf(w, hv.y, acc.y);
        acc.z = fmaf(w, hv.z, acc.z); acc.w = fmaf(w, hv.w, acc.w);
        float4 b = ((const float4*)bias)[l];
        acc.x += b.x; acc.y += b.y; acc.z += b.z; acc.w += b.w;
        if constexpr (sizeof(OutT) == 4) {
            ((float4*)((float*)out + (size_t)wid * COLS))[l] = acc;
        } else {
            ushort4 o;
            o.x = f2bf(acc.x); o.y = f2bf(acc.y); o.z = f2bf(acc.z); o.w = f2bf(acc.w);
            ((ushort4*)((unsigned short*)out + (size_t)wid * COLS))[l] = o;
        }
    }
}

// ---------------- Layer-1 quad GEMM ----------------
__global__ __launch_bounds__(256) void gemm_l1_kernel(
    const float* __restrict__ x1a, const float* __restrict__ x1b, const float* __restrict__ x2a,
    const float* __restrict__ x2b, const float* __restrict__ Wi, unsigned short* __restrict__ H1,
    unsigned short* __restrict__ H2, int nrows) {
    constexpr int CG = 16;
    const float* X = (blockIdx.y == 0) ? x1a : (blockIdx.y == 1) ? x1b
                     : (blockIdx.y == 2) ? x2a : x2b;
    const float* W = Wi + (blockIdx.y & 1) * 128 * 64;
    unsigned short* Y = (blockIdx.y < 2) ? H1 : H2;
    int ocol = (int)(blockIdx.y & 1) * 64;
    __shared__ float Ws[32][64];
    __shared__ float Xs[64][32];
    int tid = threadIdx.x;
    int row0 = blockIdx.x * 64;
    int cg = tid % CG;
    int rg = tid / CG;
    float4 acc[4];
#pragma unroll
    for (int i = 0; i < 4; ++i) acc[i] = make_float4(0.f, 0.f, 0.f, 0.f);
    for (int kc = 0; kc < 4; ++kc) {
        for (int i = tid; i < 32 * CG; i += 256) {
            int r = i / CG, c = i % CG;
            *(float4*)&Ws[r][c * 4] = *(const float4*)(W + (size_t)(kc * 32 + r) * 64 + c * 4);
        }
        for (int i = tid; i < 64 * 8; i += 256) {
            int r = i / 8, c = i % 8;
            int gr = row0 + r;
            float4 v = make_float4(0.f, 0.f, 0.f, 0.f);
            if (gr < nrows) v = *(const float4*)(X + (size_t)gr * DFEAT + kc * 32 + c * 4);
            *(float4*)&Xs[r][c * 4] = v;
        }
        __syncthreads();
#pragma unroll
        for (int k = 0; k < 32; ++k) {
            float4 w = *(float4*)&Ws[k][cg * 4];
#pragma unroll
            for (int i = 0; i < 4; ++i) {
                float a = Xs[rg * 4 + i][k];
                acc[i].x = fmaf(a, w.x, acc[i].x);
                acc[i].y = fmaf(a, w.y, acc[i].y);
                acc[i].z = fmaf(a, w.z, acc[i].z);
                acc[i].w = fmaf(a, w.w, acc[i].w);
            }
        }
        __syncthreads();
    }
#pragma unroll
    for (int i = 0; i < 4; ++i) {
        int r = row0 + rg * 4 + i;
        if (r < nrows) {
            ushort4 o;
            o.x = f2bf(acc[i].x); o.y = f2bf(acc[i].y);
            o.z = f2bf(acc[i].z); o.w = f2bf(acc[i].w);
            *(ushort4*)(Y + (size_t)r * DFEAT + ocol + cg * 4) = o;
        }
    }
}

// ---------------- prepW: Wm (2x128x128 fp32) -> bf16 transposed [l][kc][col][kk] ----------------
__global__ __launch_bounds__(256) void prepW_kernel(const float* __restrict__ Wm,
                                                    unsigned short* __restrict__ Wt) {
    int o = blockIdx.x * 256 + threadIdx.x;  // 16384 per layer
    int l = blockIdx.y;
    int kk = o & 31;
    int col = (o >> 5) & 127;
    int kc = o >> 12;
    int k = kc * 32 + kk;
    Wt[(size_t)l * 16384 + o] = f2bf(Wm[(size_t)l * 16384 + (size_t)k * 128 + col]);
}

// ---------------- MFMA fused GEMM (128->128): x = w1*relu(bn(A)) + w2*relu(bn(B)) ----------------
__global__ __launch_bounds__(256) void gemm_mfma_kernel(
    const unsigned short* __restrict__ Abf, const unsigned short* __restrict__ Bbf,
    const float* __restrict__ ss, const float* __restrict__ wout,
    const unsigned short* __restrict__ Wt, unsigned short* __restrict__ Y, int nrows) {
    __shared__ short Xs[64][128];
    int tid = threadIdx.x;
    int row0 = blockIdx.x * 64;
    int wave = tid >> 6, lane = tid & 63;
    int m = lane & 15, quad = lane >> 4;
    float w1 = wout[0], w2 = wout[1];
    for (int u = tid; u < 1024; u += 256) {
        int r = u >> 4;
        int col0 = (u & 15) * 8;
        int gr = row0 + r;
        if (gr < nrows) {
#pragma unroll
            for (int hh = 0; hh < 2; ++hh) {
                int c = col0 + hh * 4;
                float4 fa = bf4tof4(*(const ushort4*)(Abf + (size_t)gr * 128 + c));
                float4 fb = bf4tof4(*(const ushort4*)(Bbf + (size_t)gr * 128 + c));
                float4 sa = *(const float4*)(ss + c);
                float4 ha = *(const float4*)(ss + 128 + c);
                float4 sb = *(const float4*)(ss + 256 + c);
                float4 hb = *(const float4*)(ss + 384 + c);
                ushort4 o;
                o.x = f2bf(w1 * fmaxf(fmaf(fa.x, sa.x, ha.x), 0.f) +
                           w2 * fmaxf(fmaf(fb.x, sb.x, hb.x), 0.f));
                o.y = f2bf(w1 * fmaxf(fmaf(fa.y, sa.y, ha.y), 0.f) +
                           w2 * fmaxf(fmaf(fb.y, sb.y, hb.y), 0.f));
                o.z = f2bf(w1 * fmaxf(fmaf(fa.z, sa.z, ha.z), 0.f) +
                           w2 * fmaxf(fmaf(fb.z, sb.z, hb.z), 0.f));
                o.w = f2bf(w1 * fmaxf(fmaf(fa.w, sa.w, ha.w), 0.f) +
                           w2 * fmaxf(fmaf(fb.w, sb.w, hb.w), 0.f));
                *(ushort4*)&Xs[r][c] = o;
            }
        } else {
            ushort4 z = {0, 0, 0, 0};
            *(ushort4*)&Xs[r][col0] = z;
            *(ushort4*)&Xs[r][col0 + 4] = z;
        }
    }
    __syncthreads();
    f32x4 acc[8];
#pragma unroll
    for (int i = 0; i < 8; ++i) acc[i] = (f32x4){0.f, 0.f, 0.f, 0.f};
#pragma unroll
    for (int kc = 0; kc < 4; ++kc) {
        bf16x8 a = *(const bf16x8*)&Xs[wave * 16 + m][kc * 32 + quad * 8];
#pragma unroll
        for (int ct = 0; ct < 8; ++ct) {
            const short* bp = (const short*)(Wt + ((size_t)(kc * 128 + ct * 16 + m) * 32) + quad * 8);
            bf16x8 b = *(const bf16x8*)bp;
            acc[ct] = __builtin_amdgcn_mfma_f32_16x16x32_bf16(a, b, acc[ct], 0, 0, 0);
        }
    }
#pragma unroll
    for (int ct = 0; ct < 8; ++ct) {
#pragma unroll
        for (int i = 0; i < 4; ++i) {
            int gr = row0 + wave * 16 + quad * 4 + i;
            if (gr < nrows) Y[(size_t)gr * 128 + ct * 16 + m] = f2bf(acc[ct][i]);
        }
    }
}

// ---------------- VALU fused GEMM (final 128->40) ----------------
template <int CG, int RPT>
__global__ __launch_bounds__(256) void gemm_fused_kernel(
    const unsigned short* __restrict__ Abf, const unsigned short* __restrict__ Bbf,
    const float* __restrict__ ss, const float* __restrict__ wout, const float* __restrict__ W,
    unsigned short* __restrict__ Y, int nrows, int fout, int ostride) {
    __shared__ float Ws[32][CG * 4];
    __shared__ float Xs[64][32];
    int tid = threadIdx.x;
    int row0 = blockIdx.x * 64;
    int cg = tid % CG;
    int rg = tid / CG;
    float w1 = wout[0], w2 = wout[1];
    float4 acc[RPT];
#pragma unroll
    for (int i = 0; i < RPT; ++i) acc[i] = make_float4(0.f, 0.f, 0.f, 0.f);
    for (int kc = 0; kc < 4; ++kc) {
        for (int i = tid; i < 32 * CG; i += 256) {
            int r = i / CG, c = i % CG;
            float4 w;
            if ((c * 4 + 3) < fout) {
                w = *(const float4*)(W + (size_t)(kc * 32 + r) * fout + c * 4);
            } else {
                float t0 = (c * 4 + 0) < fout ? W[(size_t)(kc * 32 + r) * fout + c * 4 + 0] : 0.f;
                float t1 = (c * 4 + 1) < fout ? W[(size_t)(kc * 32 + r) * fout + c * 4 + 1] : 0.f;
                float t2 = (c * 4 + 2) < fout ? W[(size_t)(kc * 32 + r) * fout + c * 4 + 2] : 0.f;
                float t3 = (c * 4 + 3) < fout ? W[(size_t)(kc * 32 + r) * fout + c * 4 + 3] : 0.f;
                w = make_float4(t0, t1, t2, t3);
            }
            *(float4*)&Ws[r][c * 4] = w;
        }
        for (int i = tid; i < 64 * 8; i += 256) {
            int r = i / 8, c = i % 8;
            int gr = row0 + r;
            int col0 = kc * 32 + c * 4;
            float4 v = make_float4(0.f, 0.f, 0.f, 0.f);
            if (gr < nrows) {
                float4 a = bf4tof4(*(const ushort4*)(Abf + (size_t)gr * DFEAT + col0));
                float4 b = bf4tof4(*(const ushort4*)(Bbf + (size_t)gr * DFEAT + col0));
                float4 scA = *(const float4*)(ss + col0);
                float4 shA = *(const float4*)(ss + DFEAT + col0);
                float4 scB = *(const float4*)(ss + 2 * DFEAT + col0);
                float4 shB = *(const float4*)(ss + 3 * DFEAT + col0);
                v.x = w1 * fmaxf(fmaf(a.x, scA.x, shA.x), 0.f) +
                      w2 * fmaxf(fmaf(b.x, scB.x, shB.x), 0.f);
                v.y = w1 * fmaxf(fmaf(a.y, scA.y, shA.y), 0.f) +
                      w2 * fmaxf(fmaf(b.y, scB.y, shB.y), 0.f);
                v.z = w1 * fmaxf(fmaf(a.z, scA.z, shA.z), 0.f) +
                      w2 * fmaxf(fmaf(b.z, scB.z, shB.z), 0.f);
                v.w = w1 * fmaxf(fmaf(a.w, scA.w, shA.w), 0.f) +
                      w2 * fmaxf(fmaf(b.w, scB.w, shB.w), 0.f);
            }
            *(float4*)&Xs[r][c * 4] = v;
        }
        __syncthreads();
#pragma unroll
        for (int k = 0; k < 32; ++k) {
            float4 w = *(float4*)&Ws[k][cg * 4];
#pragma unroll
            for (int i = 0; i < RPT; ++i) {
                float a = Xs[rg * RPT + i][k];
                acc[i].x = fmaf(a, w.x, acc[i].x);
                acc[i].y = fmaf(a, w.y, acc[i].y);
                acc[i].z = fmaf(a, w.z, acc[i].z);
                acc[i].w = fmaf(a, w.w, acc[i].w);
            }
        }
        __syncthreads();
    }
    if (cg * 4 < fout) {
#pragma unroll
        for (int i = 0; i < RPT; ++i) {
            int r = row0 + rg * RPT + i;
            if (r < nrows) {
                ushort4 o;
                o.x = f2bf(acc[i].x); o.y = f2bf(acc[i].y);
                o.z = f2bf(acc[i].z); o.w = f2bf(acc[i].w);
                *(ushort4*)(Y + (size_t)r * ostride + cg * 4) = o;
            }
        }
    }
}

// ---------------- BN statistics: 2-level atomicAdd ----------------
__global__ __launch_bounds__(256) void stats2_kernel(const unsigned short* __restrict__ A,
                                                     const unsigned short* __restrict__ B,
                                                     float* __restrict__ stats, int nrows) {
    __shared__ float red1[256];
    __shared__ float red2[256];
    int t = threadIdx.x;
    int col = t & 127;
    int rg = t >> 7;
    const unsigned short* src = (blockIdx.y == 0) ? A : B;
    float* st = stats + (size_t)blockIdx.y * 256;
    int r0 = blockIdx.x * 128 + rg * 64;
    int r1 = min(r0 + 64, nrows);
    float s = 0.f, s2 = 0.f;
    for (int r = r0; r < r1; ++r) {
        float v = bf2f(src[(size_t)r * DFEAT + col]);
        s += v;
        s2 = fmaf(v, v, s2);
    }
    red1[t] = s;
    red2[t] = s2;
    __syncthreads();
    if (t < 128) {
        atomicAdd(&st[col], red1[t] + red1[t + 128]);
        atomicAdd(&st[DFEAT + col], red2[t] + red2[t + 128]);
    }
}

// ---------------- BN scale/shift + gates; zeros stats for next layer ----------------
__global__ __launch_bounds__(128) void gate_prep_kernel(
    float* __restrict__ statsA, float* __restrict__ statsB,
    const unsigned short* __restrict__ preA, const unsigned short* __restrict__ preB,
    const float* __restrict__ gamma, const float* __restrict__ beta,
    const float* __restrict__ gwA, const float* __restrict__ gbA,
    const float* __restrict__ gwB, const float* __restrict__ gbB,
    float* __restrict__ ss, float* __restrict__ wout, int nrows) {
    __shared__ float red[128];
    __shared__ float dotA_s;
    int t = threadIdx.x;
    float invN = 1.f / (float)nrows;
    float meanA = statsA[t] * invN;
    float varA = statsA[DFEAT + t] * invN - meanA * meanA;
    float scA = gamma[t] * rsqrtf(varA + 1e-5f);
    float shA = beta[t] - meanA * scA;
    ss[t] = scA;
    ss[DFEAT + t] = shA;
    float meanB = statsB[t] * invN;
    float varB = statsB[DFEAT + t] * invN - meanB * meanB;
    float scB = gamma[t] * rsqrtf(varB + 1e-5f);
    float shB = beta[t] - meanB * scB;
    ss[2 * DFEAT + t] = scB;
    ss[3 * DFEAT + t] = shB;
    statsA[t] = 0.f;
    statsA[DFEAT + t] = 0.f;
    statsB[t] = 0.f;
    statsB[DFEAT + t] = 0.f;
    float av = fmaxf(fmaf(bf2f(preA[(size_t)(nrows - 1) * DFEAT + t]), scA, shA), 0.f);
    red[t] = av * gwA[t];
    __syncthreads();
    for (int s = 64; s > 0; s >>= 1) {
        if (t < s) red[t] += red[t + s];
        __syncthreads();
    }
    if (t == 0) dotA_s = red[0];
    __syncthreads();
    float bv = fmaxf(fmaf(bf2f(preB[(size_t)(nrows - 1) * DFEAT + t]), scB, shB), 0.f);
    red[t] = bv * gwB[t];
    __syncthreads();
    for (int s = 64; s > 0; s >>= 1) {
        if (t < s) red[t] += red[t + s];
        __syncthreads();
    }
    if (t == 0) {
        float s1 = 1.f / (1.f + expf(-(dotA_s + gbA[0])));
        float s2 = 1.f / (1.f + expf(-(red[0] + gbB[0])));
        float tt = s1 + s2;
        wout[0] = s1 / tt;
        wout[1] = s2 / tt;
    }
}

__global__ __launch_bounds__(64) void gate_final_kernel(
    const float* __restrict__ p1, const float* __restrict__ p2,
    const float* __restrict__ w1v, const float* __restrict__ b1,
    const float* __restrict__ w2v, const float* __restrict__ b2,
    float* __restrict__ wout, int nrows, int nclass) {
    __shared__ float red[64];
    __shared__ float dot1_s;
    int t = threadIdx.x;
    float v = (t < nclass) ? p1[(size_t)(nrows - 1) * nclass + t] * w1v[t] : 0.f;
    red[t] = v;
    __syncthreads();
    for (int s = 32; s > 0; s >>= 1) {
        if (t < s) red[t] += red[t + s];
        __syncthreads();
    }
    if (t == 0) dot1_s = red[0];
    __syncthreads();
    v = (t < nclass) ? p2[(size_t)(nrows - 1) * nclass + t] * w2v[t] : 0.f;
    red[t] = v;
    __syncthreads();
    for (int s = 32; s > 0; s >>= 1) {
        if (t < s) red[t] += red[t + s];
        __syncthreads();
    }
    if (t == 0) {
        float s1 = 1.f / (1.f + expf(-(dot1_s + b1[0])));
        float s2 = 1.f / (1.f + expf(-(red[0] + b2[0])));
        float tt = s1 + s2;
        wout[0] = s1 / tt;
        wout[1] = s2 / tt;
    }
}

__global__ __launch_bounds__(256) void mix_kernel(const float* __restrict__ p1,
                                                  const float* __restrict__ p2,
                                                  const float* __restrict__ wout,
                                                  float* __restrict__ o, int n4) {
    int idx = blockIdx.x * blockDim.x + threadIdx.x;
    if (idx >= n4) return;
    float w1 = wout[0], w2 = wout[1];
    float4 a = *(const float4*)(p1 + (size_t)idx * 4);
    float4 b = *(const float4*)(p2 + (size_t)idx * 4);
    float4 r = make_float4(w1 * a.x + w2 * b.x, w1 * a.y + w2 * b.y, w1 * a.z + w2 * b.z,
                           w1 * a.w + w2 * b.w);
    *(float4*)(o + (size_t)idx * 4) = r;
}

extern "C" void kernel_launch(void* const* d_in, const int* in_sizes, int n_in, void* d_out,
                              int out_size, void* d_ws, size_t ws_size, hipStream_t stream) {
    (void)n_in; (void)out_size; (void)ws_size;
    const int N = in_sizes[0] / DFEAT;        // 50000
    const int E = in_sizes[4] / 2;            // 800000
    const int NC = in_sizes[15];              // 40

    const float* x1a = (const float*)d_in[0];
    const float* x1b = (const float*)d_in[1];
    const float* x2a = (const float*)d_in[2];
    const float* x2b = (const float*)d_in[3];
    const int* ei1 = (const int*)d_in[4];
    const int* ei2 = (const int*)d_in[5];
    const float* Wi = (const float*)d_in[6];
    const float* bi = (const float*)d_in[7];
    const float* gi = (const float*)d_in[8];
    const float* bei = (const float*)d_in[9];
    const float* Wm = (const float*)d_in[10];
    const float* bm = (const float*)d_in[11];
    const float* gm = (const float*)d_in[12];
    const float* bem = (const float*)d_in[13];
    const float* Wf = (const float*)d_in[14];
    const float* bf = (const float*)d_in[15];
    const float* fc1w1_W = (const float*)d_in[16];
    const float* fc1w1_b = (const float*)d_in[17];
    const float* fc1w2_W = (const float*)d_in[18];
    const float* fc1w2_b = (const float*)d_in[19];
    const float* aws_w1_W = (const float*)d_in[20];
    const float* aws_w1_b = (const float*)d_in[21];
    const float* aws_w2_W = (const float*)d_in[22];
    const float* aws_w2_b = (const float*)d_in[23];
    const float* fcw1_W = (const float*)d_in[24];
    const float* fcw1_b = (const float*)d_in[25];
    const float* fcw2_W = (const float*)d_in[26];
    const float* fcw2_b = (const float*)d_in[27];

    char* ws = (char*)d_ws;
    size_t off = 0;
    auto alloc = [&](size_t bytes) -> char* {
        char* p = ws + off;
        off += (bytes + 255) & ~(size_t)255;
        return p;
    };
    unsigned short* A = (unsigned short*)alloc((size_t)N * DFEAT * 2);
    unsigned short* B = (unsigned short*)alloc((size_t)N * DFEAT * 2);
    unsigned short* H1 = (unsigned short*)alloc((size_t)N * DFEAT * 2);
    unsigned short* H2 = (unsigned short*)alloc((size_t)N * DFEAT * 2);
    int* rp1 = (int*)alloc((size_t)(N + 1) * 4);
    int* rp2 = (int*)alloc((size_t)(N + 1) * 4);
    int* cnt1 = (int*)alloc((size_t)N * 4);
    int* cnt2 = (int*)alloc((size_t)N * 4);
    float* dv1 = (float*)alloc((size_t)N * 4);
    float* dv2 = (float*)alloc((size_t)N * 4);
    int* cs1 = (int*)alloc((size_t)E * 4);
    int* cs2 = (int*)alloc((size_t)E * 4);
    int* stg = (int*)alloc((size_t)2 * NRMAX * SCAP * 4);             // 10.2 MB
    int* baseB = (int*)alloc(((size_t)2 * NRMAX * SUBS << RSH) * 4);  // 16.8 MB
    int* gcount = (int*)alloc(2 * NRMAX * 4);
    unsigned short* Wt = (unsigned short*)alloc((size_t)2 * 16384 * 2);
    float* stats = (float*)alloc(2048);
    float* statsA = stats;
    float* statsB = stats + 256;
    float* ssbuf = (float*)alloc(2048);
    float* wout = (float*)alloc(256);
    int nb = (N + 2047) / 2048;  // 25
    int* bsums = (int*)alloc((size_t)2 * nb * 4);

    const int* src1 = ei1;
    const int* dst1 = ei1 + E;
    const int* src2 = ei2;
    const int* dst2 = ei2 + E;

    int nr = (N + RSZ - 1) >> RSH;            // 7
    int gemmbl = (N + 63) / 64;
    dim3 pagrid((E + EPA - 1) / EPA, 2);      // 391 x 2
    dim3 rsgrid(nr * SUBS, 2);                // 112 x 2
    dim3 ssgrid((N + 255) / 256, 2);
    dim3 agggrid((N + 3) / 4, 2);
    dim3 statgrid((N + 127) / 128, 2);
    dim3 scangrid(nb, 2);
    dim3 l1grid(gemmbl, 4);
    dim3 prepgrid(64, 2);

    // ---- CSR build (two-level counting sort, LDS atomics only) ----
    hipMemsetAsync(gcount, 0, 2 * NRMAX * 4, stream);
    prepW_kernel<<<prepgrid, 256, 0, stream>>>(Wm, Wt);
    partA_kernel<<<pagrid, 256, 0, stream>>>(src1, dst1, src2, dst2, stg, gcount, E, nr);
    histB_kernel<<<rsgrid, 256, 0, stream>>>(stg, gcount, baseB, nr);
    scanB_kernel<<<ssgrid, 256, 0, stream>>>(baseB, cnt1, cnt2, N);
    blocksum_kernel<<<scangrid, 256, 0, stream>>>(cnt1, cnt2, bsums, N, nb);
    scansums_kernel<<<1, 64, 0, stream>>>(bsums, nb, rp1, rp2, N, E, stats);
    writerp_kernel<<<scangrid, 256, 0, stream>>>(cnt1, cnt2, bsums, rp1, rp2, dv1, dv2, N, nb);
    fillC_kernel<<<rsgrid, 256, 0, stream>>>(stg, gcount, baseB, rp1, rp2, dv1, dv2,
                                             cs1, cs2, N, nr);

    // ---- Layer 1 ----
    gemm_l1_kernel<<<l1grid, 256, 0, stream>>>(x1a, x1b, x2a, x2b, Wi, H1, H2, N);
    dualagg_kernel<32, unsigned short><<<agggrid, 256, 0, stream>>>(
        H1, H2, rp1, cs1, dv1, rp2, cs2, dv2, bi, A, B, N);
    stats2_kernel<<<statgrid, 256, 0, stream>>>(A, B, stats, N);
    gate_prep_kernel<<<1, 128, 0, stream>>>(statsA, statsB, A, B, gi, bei, fc1w1_W, fc1w1_b,
                                            fc1w2_W, fc1w2_b, ssbuf, wout, N);

    // ---- Middle layer 0 (MFMA fused GEMM) ----
    gemm_mfma_kernel<<<gemmbl, 256, 0, stream>>>(A, B, ssbuf, wout, Wt, H1, N);
    dualagg_kernel<32, unsigned short><<<agggrid, 256, 0, stream>>>(
        H1, H1, rp1, cs1, dv1, rp2, cs2, dv2, bm, A, B, N);
    stats2_kernel<<<statgrid, 256, 0, stream>>>(A, B, stats, N);
    gate_prep_kernel<<<1, 128, 0, stream>>>(statsA, statsB, A, B, gm, bem, aws_w1_W, aws_w1_b,
                                            aws_w2_W, aws_w2_b, ssbuf, wout, N);

    // ---- Middle layer 1 ----
    gemm_mfma_kernel<<<gemmbl, 256, 0, stream>>>(A, B, ssbuf, wout, Wt + 16384, H1, N);
    dualagg_kernel<32, unsigned short><<<agggrid, 256, 0, stream>>>(
        H1, H1, rp1, cs1, dv1, rp2, cs2, dv2, bm + 128, A, B, N);
    stats2_kernel<<<statgrid, 256, 0, stream>>>(A, B, stats, N);
    gate_prep_kernel<<<1, 128, 0, stream>>>(statsA, statsB, A, B, gm + 128, bem + 128,
                                            aws_w1_W + 128, aws_w1_b + 1, aws_w2_W + 128,
                                            aws_w2_b + 1, ssbuf, wout, N);

    // ---- Final layer ----
    float* out0 = (float*)d_out;
    float* p1 = out0 + (size_t)N * NC;
    float* p2 = out0 + (size_t)2 * N * NC;
    gemm_fused_kernel<16, 4><<<gemmbl, 256, 0, stream>>>(A, B, ssbuf, wout, Wf, H2, N, NC, NC);
    dualagg_kernel<10, float><<<agggrid, 256, 0, stream>>>(H2, H2, rp1, cs1, dv1, rp2, cs2, dv2,
                                                           bf, p1, p2, N);
    gate_final_kernel<<<1, 64, 0, stream>>>(p1, p2, fcw1_W, fcw1_b, fcw2_W, fcw2_b, wout, N, NC);
    mix_kernel<<<(N * NC / 4 + 255) / 256, 256, 0, stream>>>(p1, p2, wout, out0, N * NC / 4);
}